// Round 15
// baseline (117.622 us; speedup 1.0000x reference)
//
#include <hip/hip_runtime.h>
#include <float.h>

// HaloAttn: x(4,128,128,128) f32 -> out(4,128,128,128) f32
// BS=8, HS=3, WIN=14, NH=8, DQK=DV=16, SCALE=0.25
//
// k0: conv_w      weights -> hi/lo bf16, frag-major W'[rb][kc][lr][8]
// k1: gemm_split  q=x@q_w^T, kv=x@kv_w^T -> ws bf16 head-major (split MFMA)
// k2: halo_attn   R15 (=R14 fixed): row-aligned key space (g=wy*16+wx),
//                 pointer-walk bias reads, mask+sum via valid8 MFMA
// k3: gemm_split  d_out = d_out @ proj_w^T + proj_b (in place)
//
// Key space: g = wy*16+wx (wy<14, wx<16; wx>=14 or out-of-image = invalid).
// Permutation (pair m, sub-tile s, A-row i): key = 32m + (i>>2)*8 + 4s + (i&3).
// QK C-frag: lane(lr,cA) reg r holds S for key kb+4s+r, kb=32m+cA*8; those
// keys share window row wy=2m+(cA>>1), wx=(cA&1)*8 + (4s+r) -> bias indices
// consecutive descending -> base pointer bptr[7-(4s+r)], bptr walks -42/m.
// Denominator: accs = mfma(valid8, pb, accs) -> every reg = masked sum.
// Invalid keys: bounded-garbage p (guarded bias idx in [-2,440], K<-pixel 0),
// zeroed exactly by valid8 (sum) and zeroed V^T rows (PV).
//
// Head-major ws: kv[8][65536][32] ushort @0 (32MB) | q[8][65536][16] @32M
//   | whi' @48M | wlo' (128KB each, frag-major).

typedef float f32x4 __attribute__((ext_vector_type(4)));
typedef short s16x4 __attribute__((ext_vector_type(4)));
typedef short s16x8 __attribute__((ext_vector_type(8)));
typedef unsigned int u32x2 __attribute__((ext_vector_type(2)));
typedef unsigned int u32x4 __attribute__((ext_vector_type(4)));

__device__ inline ushort f2bf(float f) {   // RNE float->bf16 (cold paths)
    unsigned u = __float_as_uint(f);
    return (ushort)((u + 0x7FFF + ((u >> 16) & 1)) >> 16);
}
__device__ inline float bf2f(ushort h) { return __uint_as_float((unsigned)h << 16); }
__device__ inline unsigned cvtpk(float a, float b) {   // D[15:0]=bf16(a), D[31:16]=bf16(b)
    unsigned r;
    asm("v_cvt_pk_bf16_f32 %0, %1, %2" : "=v"(r) : "v"(a), "v"(b));
    return r;
}
#if __has_builtin(__builtin_amdgcn_exp2f)
#define EXP2(x) __builtin_amdgcn_exp2f(x)
#else
#define EXP2(x) exp2f(x)
#endif

// ---------------------------------------------------------------------------
// Weight split into FRAG-MAJOR layout (rows 0-127 q_w, 128-383 kv_w, 384-511
// proj_w): W'[(row>>4)][col>>3][row&15][col&7].
__global__ __launch_bounds__(256) void conv_w(
    const float* __restrict__ q_w, const float* __restrict__ kv_w,
    const float* __restrict__ proj_w, ushort* whi, ushort* wlo)
{
    const int g = blockIdx.x * 256 + threadIdx.x;      // 0..65535
    const int row = g >> 7, col = g & 127;
    const float v = (row < 128) ? q_w[row * 128 + col]
                  : (row < 384) ? kv_w[(row - 128) * 128 + col]
                                : proj_w[(row - 384) * 128 + col];
    const ushort h = f2bf(v);
    const int off = ((row >> 4) * 2048) + ((col >> 3) * 128) + ((row & 15) * 8) + (col & 7);
    whi[off] = h;
    wlo[off] = f2bf(v - bf2f(h));
}

// ---------------------------------------------------------------------------
// Split-bf16 MFMA GEMM (unchanged from R13).
__global__ __launch_bounds__(256) void gemm_split(
    const float* A,                                   // [M][128] fp32
    const ushort* __restrict__ Whi, const ushort* __restrict__ Wlo,
    int wbase, int ntc, int tok1,
    ushort* qb, ushort* kvb, float* outf, const float* __restrict__ bias)
{
    __shared__ ushort Ah[128 * 128];   // [row][k] swizzled 16B chunks, 32KB
    __shared__ ushort Al[128 * 128];

    const int t = threadIdx.x;
    const int row0 = blockIdx.x * 128;
    const int w = t >> 6, l = t & 63;
    const int wm = w >> 1, wn = w & 1;
    const int lr = l & 15, cA = l >> 4;

#pragma unroll
    for (int i = 0; i < 16; ++i) {
        const int idx = t + i * 256;
        const int p = idx >> 5, fc = idx & 31;         // row, float4-col
        const float4 v = *(const float4*)(A + (size_t)(row0 + p) * 128 + fc * 4);
        const int base = p * 128 + (((fc >> 1) ^ (p & 7)) << 3) + (fc & 1) * 4;
        const unsigned h01 = cvtpk(v.x, v.y), h23 = cvtpk(v.z, v.w);
        *(u32x2*)&Ah[base] = (u32x2){h01, h23};
        const float hx = __uint_as_float(h01 << 16);
        const float hy = __uint_as_float(h01 & 0xFFFF0000u);
        const float hz = __uint_as_float(h23 << 16);
        const float hw = __uint_as_float(h23 & 0xFFFF0000u);
        *(u32x2*)&Al[base] = (u32x2){ cvtpk(v.x - hx, v.y - hy),
                                      cvtpk(v.z - hz, v.w - hw) };
    }
    __syncthreads();

#pragma unroll 1
    for (int nt = 0; nt < ntc; ++nt) {
        f32x4 acc[4][4];
#pragma unroll
        for (int mf = 0; mf < 4; ++mf)
#pragma unroll
            for (int nf = 0; nf < 4; ++nf) acc[mf][nf] = (f32x4){0.f,0.f,0.f,0.f};

#pragma unroll 1
        for (int kk = 0; kk < 4; ++kk) {
            s16x8 wh[4], wl[4];
#pragma unroll
            for (int nf = 0; nf < 4; ++nf) {
                const int rb = (wbase >> 4) + nt * 8 + wn * 4 + nf;
                const size_t off = (size_t)rb * 2048 + (kk * 4 + cA) * 128 + lr * 8;
                wh[nf] = *(const s16x8*)&Whi[off];
                wl[nf] = *(const s16x8*)&Wlo[off];
            }
#pragma unroll
            for (int mf = 0; mf < 4; ++mf) {
                const int p = wm * 64 + mf * 16 + lr;
                const int off = p * 128 + ((((kk << 2) + cA) ^ (p & 7)) << 3);
                const s16x8 xh = *(const s16x8*)&Ah[off];
                const s16x8 xl = *(const s16x8*)&Al[off];
#pragma unroll
                for (int nf = 0; nf < 4; ++nf) {
                    acc[mf][nf] = __builtin_amdgcn_mfma_f32_16x16x32_bf16(
                                      wh[nf], xh, acc[mf][nf], 0, 0, 0);
                    acc[mf][nf] = __builtin_amdgcn_mfma_f32_16x16x32_bf16(
                                      wh[nf], xl, acc[mf][nf], 0, 0, 0);
                    acc[mf][nf] = __builtin_amdgcn_mfma_f32_16x16x32_bf16(
                                      wl[nf], xh, acc[mf][nf], 0, 0, 0);
                }
            }
        }

#pragma unroll
        for (int mf = 0; mf < 4; ++mf) {
            const size_t pix = row0 + wm * 64 + mf * 16 + lr;
#pragma unroll
            for (int nf = 0; nf < 4; ++nf) {
                const int chan = wn * 64 + nf * 16 + cA * 4;
                const f32x4 o = acc[mf][nf];
                if (tok1) {
                    const u32x2 pk = (u32x2){ cvtpk(o[0], o[1]), cvtpk(o[2], o[3]) };
                    if (nt == 0) {
                        const int head = wn * 4 + nf;
                        *(u32x2*)(qb + ((size_t)head << 20) + pix * 16 + (chan & 15)) = pk;
                    } else {
                        const int gchan = (nt - 1) * 128 + chan;
                        const int head = gchan >> 5;
                        *(u32x2*)(kvb + ((size_t)head << 21) + pix * 32 + (gchan & 31)) = pk;
                    }
                } else {
                    const float4 bv = *(const float4*)(bias + chan);
                    f32x4 r = o;
                    r[0] += bv.x; r[1] += bv.y; r[2] += bv.z; r[3] += bv.w;
                    *(f32x4*)(outf + pix * 128 + chan) = r;
                }
            }
        }
    }
}

// ---------------------------------------------------------------------------
// MFMA halo attention, R15. grid(256 spatial, 8 head, 2 batch-pair),
// 256 thr = 4 waves = 2 batches x 2 q-halves.
__global__ __launch_bounds__(256) void halo_attn(
    float* out,                           // d_out fp32 (65536 x 128)
    const ushort* __restrict__ qg,        // ws q bf16 [8][65536][16] head-major
    const ushort* __restrict__ kvg,       // ws kv bf16 [8][65536][32] head-major
    const float* __restrict__ pos_table)  // (729, 8)
{
    __shared__ ushort VT[2][16][232];     // [local batch][dim][key]  14848 B
    __shared__ float  bias_l[444];        // logical idx -2..441 (2-entry guard)
    __shared__ int    keyoff[256];        // byte offset into kv slice (0 if invalid)
    __shared__ ushort vbf[232];           // valid ? bf16(1.0) : 0

    const int t  = threadIdx.x;
    const int bi = blockIdx.x, head = blockIdx.y, bpair = blockIdx.z;
    const int by = bi >> 4, bx = bi & 15;
    const int w  = t >> 6;
    const int lb = w >> 1;                 // local batch 0/1
    const int qh = w & 1;                  // q-half
    const int batch = bpair * 2 + lb;
    const int l  = t & 63;
    const int lr = l & 15;
    const int cA = l >> 4;

    const char* kvh = (const char*)(kvg + ((size_t)head << 21) + ((size_t)batch << 19));

    // ---- per-block LUTs: key g = wy*16+wx (wy = g>>4, wx = g&15)
    if (t < 224) {
        const int wy = t >> 4, wx = t & 15;
        const int py = by * 8 + wy - 3, px = bx * 8 + wx - 3;
        const bool valid = (wx < 14) && ((unsigned)py < 128u) && ((unsigned)px < 128u);
        keyoff[t] = valid ? ((py * 128 + px) * 64) : 0;
        vbf[t]    = valid ? (ushort)0x3F80 : (ushort)0;
    } else {
        keyoff[t] = 0;
        if (t < 232) vbf[t] = 0;
    }
    for (int i = t; i < 444; i += 256) {
        float v = 0.f;                     // guard entries (idx -2,-1) = 0 (bounded)
        if (i >= 2) {
            const int r = i - 2, ry = r / 21, rx = r - ry * 21;
            v = pos_table[((ry + 3) * 27 + rx + 3) * 8 + head] * 1.44269504f;
        }
        bias_l[i] = v;
    }
    __syncthreads();

    // ---- stage V^T (zeroed for invalid keys): 2 waves/batch, l2 = qh*64+l
    {
        const int l2 = qh * 64 + l;
        if (l2 < 112) {
            const char* base = kvh + 32;   // v = d16..31 of each record
            const bool v0 = vbf[2 * l2] != 0;
            const bool v1 = vbf[2 * l2 + 1] != 0;
            const s16x8 z = (s16x8){0,0,0,0,0,0,0,0};
            const char* s0 = base + keyoff[2 * l2];
            const char* s1 = base + keyoff[2 * l2 + 1];
            const s16x8 a0 = v0 ? *(const s16x8*)s0 : z;
            const s16x8 a1 = v0 ? *(const s16x8*)(s0 + 16) : z;
            const s16x8 c0 = v1 ? *(const s16x8*)s1 : z;
            const s16x8 c1 = v1 ? *(const s16x8*)(s1 + 16) : z;
#pragma unroll
            for (int j = 0; j < 8; ++j) {
                *(unsigned*)&VT[lb][j][2 * l2] =
                    ((unsigned)(ushort)c0[j] << 16) | (ushort)a0[j];
                *(unsigned*)&VT[lb][j + 8][2 * l2] =
                    ((unsigned)(ushort)c1[j] << 16) | (ushort)a1[j];
            }
        }
    }
    __syncthreads();

    // ---- per-wave setup: 2 q-tiles (qt = qh*2 + j)
    const int gbase = ((lr >> 2) << 3) + (lr & 3);   // key-permutation base
    const ushort* qhp = qg + ((size_t)head << 20);
    const int wy0 = cA >> 1, wx0 = (cA & 1) * 8;     // this lane's m=0 window row/col
    s16x8 qf[2];
    float* optr[2];
    const float* bptr[2];                            // bias ptr at group idx_min
#pragma unroll
    for (int j = 0; j < 2; ++j) {
        const int q = (qh * 2 + j) * 16 + lr;
        const int qy = q >> 3, qx = q & 7;
        const size_t pix = ((size_t)(batch * 128 + by * 8 + qy)) * 128 + bx * 8 + qx;
        optr[j] = out + pix * 128 + head * 16 + cA * 4;
        // idx_min(m=0) = (qy+13-wy0)*21 + (qx+6-wx0); +2 array guard offset
        bptr[j] = bias_l + 2 + (qy + 13 - wy0) * 21 + (qx + 6 - wx0);
#pragma unroll
        for (int k = 0; k < 8; ++k) qf[j][k] = 0;
        if (cA < 2)
            qf[j] = *(const s16x8*)(qhp + pix * 16 + cA * 8);
    }

    f32x4 accv[2], accs[2];
#pragma unroll
    for (int j = 0; j < 2; ++j) {
        accv[j] = (f32x4){0.f, 0.f, 0.f, 0.f};
        accs[j] = (f32x4){0.f, 0.f, 0.f, 0.f};
    }

    // prefetch pair 0 (invalid keys read pixel 0 -> bounded garbage, later zeroed)
    s16x8 ak0 = *(const s16x8*)(kvh + keyoff[gbase]     + cA * 16);
    s16x8 ak1 = *(const s16x8*)(kvh + keyoff[gbase + 4] + cA * 16);

#pragma unroll 1
    for (int m = 0; m < 7; ++m) {
        const int nx = 32 * (m + 1) + gbase;
        const s16x8 nk0 = *(const s16x8*)(kvh + keyoff[nx]     + cA * 16);
        const s16x8 nk1 = *(const s16x8*)(kvh + keyoff[nx + 4] + cA * 16);

        const int kb = 32 * m + cA * 8;                 // this lane's 8 keys
        const s16x8 vt  = *(const s16x8*)&VT[lb][lr][kb];  // PV A-frag (dim=lr)
        const s16x8 vld = *(const s16x8*)&vbf[kb];         // sum A-frag (valid bf16)

#pragma unroll
        for (int j = 0; j < 2; ++j) {
            const f32x4 sf0 = __builtin_amdgcn_mfma_f32_16x16x32_bf16(
                                  ak0, qf[j], (f32x4){0.f, 0.f, 0.f, 0.f}, 0, 0, 0);
            const f32x4 sf1 = __builtin_amdgcn_mfma_f32_16x16x32_bf16(
                                  ak1, qf[j], (f32x4){0.f, 0.f, 0.f, 0.f}, 0, 0, 0);
            // bias: key kb+4s+r is window col wx0+4s+r -> bq[7-(4s+r)]
            const float* bq = bptr[j];
            float pr0[4], pr1[4];
#pragma unroll
            for (int r = 0; r < 4; ++r)
                pr0[r] = EXP2(fmaf(sf0[r], 0.36067376f, bq[7 - r]));
#pragma unroll
            for (int r = 0; r < 4; ++r)
                pr1[r] = EXP2(fmaf(sf1[r], 0.36067376f, bq[3 - r]));

            const u32x4 pk = (u32x4){ cvtpk(pr0[0], pr0[1]), cvtpk(pr0[2], pr0[3]),
                                      cvtpk(pr1[0], pr1[1]), cvtpk(pr1[2], pr1[3]) };
            const s16x8 pb = *(const s16x8*)&pk;       // PV B-frag: keys kb..kb+7
            accv[j] = __builtin_amdgcn_mfma_f32_16x16x32_bf16(vt,  pb, accv[j], 0, 0, 0);
            accs[j] = __builtin_amdgcn_mfma_f32_16x16x32_bf16(vld, pb, accs[j], 0, 0, 0);
        }
        bptr[0] -= 42;                                 // next window row pair
        bptr[1] -= 42;
        ak0 = nk0;
        ak1 = nk1;
    }

    // ---- normalize: every accs reg = full masked sum for q=lr
#pragma unroll
    for (int j = 0; j < 2; ++j) {
        const float inv = 1.0f / accs[j][0];
        *(f32x4*)optr[j] = accv[j] * inv;
    }
}

// ---------------------------------------------------------------------------
extern "C" void kernel_launch(void* const* d_in, const int* in_sizes, int n_in,
                              void* d_out, int out_size, void* d_ws, size_t ws_size,
                              hipStream_t stream) {
    const float* x      = (const float*)d_in[0];
    const float* q_w    = (const float*)d_in[1];
    const float* kv_w   = (const float*)d_in[2];
    const float* pt     = (const float*)d_in[3];
    const float* proj_w = (const float*)d_in[4];
    const float* proj_b = (const float*)d_in[5];
    float* out = (float*)d_out;

    ushort* ykvb = (ushort*)d_ws;                                   // 32 MB head-major
    ushort* qb   = (ushort*)((char*)d_ws + 33554432);               // 16 MB head-major
    ushort* whi  = (ushort*)((char*)d_ws + 33554432 + 16777216);    // 128 KB frag-major
    ushort* wlo  = whi + 65536;                                     // 128 KB

    const dim3 blk(256);
    conv_w<<<dim3(256), blk, 0, stream>>>(q_w, kv_w, proj_w, whi, wlo);
    gemm_split<<<dim3(512), blk, 0, stream>>>(x, whi, wlo, 0, 3, 1,
                                              qb, ykvb, nullptr, nullptr);
    halo_attn<<<dim3(256, 8, 2), blk, 0, stream>>>(out, qb, ykvb, pt);
    gemm_split<<<dim3(512), blk, 0, stream>>>(out, whi, wlo, 384, 1, 0,
                                              nullptr, nullptr, out, proj_b);
}

// Round 17
// 94.764 us; speedup vs baseline: 1.2412x; 1.2412x over previous
//
#include <hip/hip_runtime.h>
#include <float.h>

// HaloAttn: x(4,128,128,128) f32 -> out(4,128,128,128) f32
// BS=8, HS=3, WIN=14, NH=8, DQK=DV=16, SCALE=0.25
//
// k0: conv_w      weights -> hi/lo bf16, frag-major W'[rb][kc][lr][8]
// k1: gemm_split  q=x@q_w^T, kv=x@kv_w^T -> ws bf16 head-major (split MFMA)
// k2: halo_attn   R17 bisect: R16 structure (1 batch/block, wave=q-tile,
//                 8 blocks/CU) + R15 data path (global ak gathers, no Klds).
// k3: gemm_split  d_out = d_out @ proj_w^T + proj_b (in place)
//
// Key space: g = wy*16+wx (wy<14, wx<16; wx>=14 or out-of-image = invalid).
// Permutation (pair m, sub-tile s, A-row i): key = 32m + (i>>2)*8 + 4s + (i&3).
// QK C-frag: lane(lr,cA) reg r holds S for key kb+4s+r, kb=32m+cA*8; those
// keys share window row wy=2m+(cA>>1), wx=(cA&1)*8+(4s+r) -> bias indices
// consecutive descending: bq[7-(4s+r)], bq walks -42/m (pointer-walk, R15).
// Denominator: accs = mfma(valid8, pb, accs) -> every reg = masked sum (R15).
// Invalid keys: bounded-garbage p (K<-pixel 0, guarded bias idx in [-2,440]),
// zeroed exactly by vbf (sum) and zeroed V^T rows (PV).
//
// Head-major ws: kv[8][65536][32] ushort @0 (32MB) | q[8][65536][16] @32M
//   | whi' @48M | wlo' (128KB each, frag-major).

typedef float f32x4 __attribute__((ext_vector_type(4)));
typedef short s16x4 __attribute__((ext_vector_type(4)));
typedef short s16x8 __attribute__((ext_vector_type(8)));
typedef unsigned int u32x2 __attribute__((ext_vector_type(2)));
typedef unsigned int u32x4 __attribute__((ext_vector_type(4)));

__device__ inline ushort f2bf(float f) {   // RNE float->bf16 (cold paths)
    unsigned u = __float_as_uint(f);
    return (ushort)((u + 0x7FFF + ((u >> 16) & 1)) >> 16);
}
__device__ inline float bf2f(ushort h) { return __uint_as_float((unsigned)h << 16); }
__device__ inline unsigned cvtpk(float a, float b) {   // D[15:0]=bf16(a), D[31:16]=bf16(b)
    unsigned r;
    asm("v_cvt_pk_bf16_f32 %0, %1, %2" : "=v"(r) : "v"(a), "v"(b));
    return r;
}
#if __has_builtin(__builtin_amdgcn_exp2f)
#define EXP2(x) __builtin_amdgcn_exp2f(x)
#else
#define EXP2(x) exp2f(x)
#endif

// ---------------------------------------------------------------------------
// Weight split into FRAG-MAJOR layout (rows 0-127 q_w, 128-383 kv_w, 384-511
// proj_w): W'[(row>>4)][col>>3][row&15][col&7].
__global__ __launch_bounds__(256) void conv_w(
    const float* __restrict__ q_w, const float* __restrict__ kv_w,
    const float* __restrict__ proj_w, ushort* whi, ushort* wlo)
{
    const int g = blockIdx.x * 256 + threadIdx.x;      // 0..65535
    const int row = g >> 7, col = g & 127;
    const float v = (row < 128) ? q_w[row * 128 + col]
                  : (row < 384) ? kv_w[(row - 128) * 128 + col]
                                : proj_w[(row - 384) * 128 + col];
    const ushort h = f2bf(v);
    const int off = ((row >> 4) * 2048) + ((col >> 3) * 128) + ((row & 15) * 8) + (col & 7);
    whi[off] = h;
    wlo[off] = f2bf(v - bf2f(h));
}

// ---------------------------------------------------------------------------
// Split-bf16 MFMA GEMM (unchanged, R13-proven).
__global__ __launch_bounds__(256) void gemm_split(
    const float* A,                                   // [M][128] fp32
    const ushort* __restrict__ Whi, const ushort* __restrict__ Wlo,
    int wbase, int ntc, int tok1,
    ushort* qb, ushort* kvb, float* outf, const float* __restrict__ bias)
{
    __shared__ ushort Ah[128 * 128];   // [row][k] swizzled 16B chunks, 32KB
    __shared__ ushort Al[128 * 128];

    const int t = threadIdx.x;
    const int row0 = blockIdx.x * 128;
    const int w = t >> 6, l = t & 63;
    const int wm = w >> 1, wn = w & 1;
    const int lr = l & 15, cA = l >> 4;

#pragma unroll
    for (int i = 0; i < 16; ++i) {
        const int idx = t + i * 256;
        const int p = idx >> 5, fc = idx & 31;         // row, float4-col
        const float4 v = *(const float4*)(A + (size_t)(row0 + p) * 128 + fc * 4);
        const int base = p * 128 + (((fc >> 1) ^ (p & 7)) << 3) + (fc & 1) * 4;
        const unsigned h01 = cvtpk(v.x, v.y), h23 = cvtpk(v.z, v.w);
        *(u32x2*)&Ah[base] = (u32x2){h01, h23};
        const float hx = __uint_as_float(h01 << 16);
        const float hy = __uint_as_float(h01 & 0xFFFF0000u);
        const float hz = __uint_as_float(h23 << 16);
        const float hw = __uint_as_float(h23 & 0xFFFF0000u);
        *(u32x2*)&Al[base] = (u32x2){ cvtpk(v.x - hx, v.y - hy),
                                      cvtpk(v.z - hz, v.w - hw) };
    }
    __syncthreads();

#pragma unroll 1
    for (int nt = 0; nt < ntc; ++nt) {
        f32x4 acc[4][4];
#pragma unroll
        for (int mf = 0; mf < 4; ++mf)
#pragma unroll
            for (int nf = 0; nf < 4; ++nf) acc[mf][nf] = (f32x4){0.f,0.f,0.f,0.f};

#pragma unroll 1
        for (int kk = 0; kk < 4; ++kk) {
            s16x8 wh[4], wl[4];
#pragma unroll
            for (int nf = 0; nf < 4; ++nf) {
                const int rb = (wbase >> 4) + nt * 8 + wn * 4 + nf;
                const size_t off = (size_t)rb * 2048 + (kk * 4 + cA) * 128 + lr * 8;
                wh[nf] = *(const s16x8*)&Whi[off];
                wl[nf] = *(const s16x8*)&Wlo[off];
            }
#pragma unroll
            for (int mf = 0; mf < 4; ++mf) {
                const int p = wm * 64 + mf * 16 + lr;
                const int off = p * 128 + ((((kk << 2) + cA) ^ (p & 7)) << 3);
                const s16x8 xh = *(const s16x8*)&Ah[off];
                const s16x8 xl = *(const s16x8*)&Al[off];
#pragma unroll
                for (int nf = 0; nf < 4; ++nf) {
                    acc[mf][nf] = __builtin_amdgcn_mfma_f32_16x16x32_bf16(
                                      wh[nf], xh, acc[mf][nf], 0, 0, 0);
                    acc[mf][nf] = __builtin_amdgcn_mfma_f32_16x16x32_bf16(
                                      wh[nf], xl, acc[mf][nf], 0, 0, 0);
                    acc[mf][nf] = __builtin_amdgcn_mfma_f32_16x16x32_bf16(
                                      wl[nf], xh, acc[mf][nf], 0, 0, 0);
                }
            }
        }

#pragma unroll
        for (int mf = 0; mf < 4; ++mf) {
            const size_t pix = row0 + wm * 64 + mf * 16 + lr;
#pragma unroll
            for (int nf = 0; nf < 4; ++nf) {
                const int chan = wn * 64 + nf * 16 + cA * 4;
                const f32x4 o = acc[mf][nf];
                if (tok1) {
                    const u32x2 pk = (u32x2){ cvtpk(o[0], o[1]), cvtpk(o[2], o[3]) };
                    if (nt == 0) {
                        const int head = wn * 4 + nf;
                        *(u32x2*)(qb + ((size_t)head << 20) + pix * 16 + (chan & 15)) = pk;
                    } else {
                        const int gchan = (nt - 1) * 128 + chan;
                        const int head = gchan >> 5;
                        *(u32x2*)(kvb + ((size_t)head << 21) + pix * 32 + (gchan & 31)) = pk;
                    }
                } else {
                    const float4 bv = *(const float4*)(bias + chan);
                    f32x4 r = o;
                    r[0] += bv.x; r[1] += bv.y; r[2] += bv.z; r[3] += bv.w;
                    *(f32x4*)(outf + pix * 128 + chan) = r;
                }
            }
        }
    }
}

// ---------------------------------------------------------------------------
// MFMA halo attention, R17. grid(256 spatial, 8 head, 4 batch), 256 thr =
// 4 waves = 4 q-tiles of one (batch, head, spatial block). LDS ~10.7KB ->
// 8 blocks/CU. ak from GLOBAL via keyoff LUT + 1-deep prefetch (R15-proven).
__global__ __launch_bounds__(256) void halo_attn(
    float* out,                           // d_out fp32 (65536 x 128)
    const ushort* __restrict__ qg,        // ws q bf16 [8][65536][16] head-major
    const ushort* __restrict__ kvg,       // ws kv bf16 [8][65536][32] head-major
    const float* __restrict__ pos_table)  // (729, 8)
{
    __shared__ ushort VT[16][232];        // [dim][key] bf16                 7424 B
    __shared__ float  bias_l[444];        // logical idx -2..441 (2-entry guard)
    __shared__ int    keyoff[256];        // byte offset into kv slice (0 if invalid/pad)
    __shared__ ushort vbf[232];           // valid ? bf16(1.0) : 0

    const int t  = threadIdx.x;
    const int bi = blockIdx.x, head = blockIdx.y, batch = blockIdx.z;
    const int by = bi >> 4, bx = bi & 15;
    const int w  = t >> 6;                 // wave id = q-tile
    const int l  = t & 63;
    const int lr = l & 15;
    const int cA = l >> 4;

    const char* kvh = (const char*)(kvg + ((size_t)head << 21) + ((size_t)batch << 19));

    // ---- per-block LUTs: key g = wy*16+wx (wy = g>>4, wx = g&15)
    if (t < 224) {
        const int wy = t >> 4, wx = t & 15;
        const int py = by * 8 + wy - 3, px = bx * 8 + wx - 3;
        const bool valid = (wx < 14) && ((unsigned)py < 128u) && ((unsigned)px < 128u);
        keyoff[t] = valid ? ((py * 128 + px) * 64) : 0;
        vbf[t]    = valid ? (ushort)0x3F80 : (ushort)0;
    } else {
        keyoff[t] = 0;                     // prefetch pad
        if (t < 232) vbf[t] = 0;
    }
    for (int i = t; i < 444; i += 256) {
        float v = 0.f;                     // guard entries (idx -2,-1) = 0 (bounded)
        if (i >= 2) {
            const int r = i - 2, ry = r / 21, rx = r - ry * 21;
            v = pos_table[((ry + 3) * 27 + rx + 3) * 8 + head] * 1.44269504f;
        }
        bias_l[i] = v;
    }
    __syncthreads();

    // ---- stage V^T (zeroed for invalid keys): threads 0..223, key t each
    if (t < 224) {
        const char* src = kvh + keyoff[t] + 32;        // v = d16..31 of record
        const bool valid = vbf[t] != 0;
        const s16x8 z = (s16x8){0,0,0,0,0,0,0,0};
        const s16x8 v0 = valid ? *(const s16x8*)src : z;
        const s16x8 v1 = valid ? *(const s16x8*)(src + 16) : z;
#pragma unroll
        for (int j = 0; j < 8; ++j) {
            VT[j][t]     = (ushort)v0[j];
            VT[j + 8][t] = (ushort)v1[j];
        }
    }
    __syncthreads();

    // ---- per-wave setup: q-tile = w
    const int gbase = ((lr >> 2) << 3) + (lr & 3);   // key-permutation base
    const int wy0 = cA >> 1, wx0 = (cA & 1) * 8;     // lane's m=0 window row/col
    const int q = w * 16 + lr;
    const int qy = q >> 3, qx = q & 7;
    const size_t pix = ((size_t)(batch * 128 + by * 8 + qy)) * 128 + bx * 8 + qx;
    float* optr = out + pix * 128 + head * 16 + cA * 4;
    // idx_min(m=0) = (qy+13-wy0)*21 + (qx+6-wx0); +2 guard offset
    const float* bptr = bias_l + 2 + (qy + 13 - wy0) * 21 + (qx + 6 - wx0);

    s16x8 qf;
#pragma unroll
    for (int k = 0; k < 8; ++k) qf[k] = 0;
    if (cA < 2)
        qf = *(const s16x8*)(qg + ((size_t)head << 20) + pix * 16 + cA * 8);

    f32x4 accv = (f32x4){0.f, 0.f, 0.f, 0.f};
    f32x4 accs = (f32x4){0.f, 0.f, 0.f, 0.f};

    // prefetch pair 0 (invalid keys read pixel 0 -> bounded garbage, zeroed later)
    s16x8 ak0 = *(const s16x8*)(kvh + keyoff[gbase]     + cA * 16);
    s16x8 ak1 = *(const s16x8*)(kvh + keyoff[gbase + 4] + cA * 16);

#pragma unroll 1
    for (int m = 0; m < 7; ++m) {
        const int nx = 32 * (m + 1) + gbase;
        const s16x8 nk0 = *(const s16x8*)(kvh + keyoff[nx]     + cA * 16);
        const s16x8 nk1 = *(const s16x8*)(kvh + keyoff[nx + 4] + cA * 16);

        const int kb = 32 * m + cA * 8;                 // this lane's 8 keys
        const s16x8 vt  = *(const s16x8*)&VT[lr][kb];   // PV A-frag (dim=lr)
        const s16x8 vld = *(const s16x8*)&vbf[kb];      // sum A-frag (valid bf16)

        const f32x4 sf0 = __builtin_amdgcn_mfma_f32_16x16x32_bf16(
                              ak0, qf, (f32x4){0.f, 0.f, 0.f, 0.f}, 0, 0, 0);
        const f32x4 sf1 = __builtin_amdgcn_mfma_f32_16x16x32_bf16(
                              ak1, qf, (f32x4){0.f, 0.f, 0.f, 0.f}, 0, 0, 0);

        // bias: key kb+4s+r is window col wx0+4s+r -> bq[7-(4s+r)]
        const float* bq = bptr - m * 42;
        float pr0[4], pr1[4];
#pragma unroll
        for (int r = 0; r < 4; ++r)
            pr0[r] = EXP2(fmaf(sf0[r], 0.36067376f, bq[7 - r]));
#pragma unroll
        for (int r = 0; r < 4; ++r)
            pr1[r] = EXP2(fmaf(sf1[r], 0.36067376f, bq[3 - r]));

        const u32x4 pk = (u32x4){ cvtpk(pr0[0], pr0[1]), cvtpk(pr0[2], pr0[3]),
                                  cvtpk(pr1[0], pr1[1]), cvtpk(pr1[2], pr1[3]) };
        const s16x8 pb = *(const s16x8*)&pk;           // PV B-frag: keys kb..kb+7
        accv = __builtin_amdgcn_mfma_f32_16x16x32_bf16(vt,  pb, accv, 0, 0, 0);
        accs = __builtin_amdgcn_mfma_f32_16x16x32_bf16(vld, pb, accs, 0, 0, 0);

        ak0 = nk0;
        ak1 = nk1;
    }

    // ---- normalize: every accs reg = full masked sum for q = w*16+lr
    const float inv = 1.0f / accs[0];
    *(f32x4*)optr = accv * inv;
}

// ---------------------------------------------------------------------------
extern "C" void kernel_launch(void* const* d_in, const int* in_sizes, int n_in,
                              void* d_out, int out_size, void* d_ws, size_t ws_size,
                              hipStream_t stream) {
    const float* x      = (const float*)d_in[0];
    const float* q_w    = (const float*)d_in[1];
    const float* kv_w   = (const float*)d_in[2];
    const float* pt     = (const float*)d_in[3];
    const float* proj_w = (const float*)d_in[4];
    const float* proj_b = (const float*)d_in[5];
    float* out = (float*)d_out;

    ushort* ykvb = (ushort*)d_ws;                                   // 32 MB head-major
    ushort* qb   = (ushort*)((char*)d_ws + 33554432);               // 16 MB head-major
    ushort* whi  = (ushort*)((char*)d_ws + 33554432 + 16777216);    // 128 KB frag-major
    ushort* wlo  = whi + 65536;                                     // 128 KB

    const dim3 blk(256);
    conv_w<<<dim3(256), blk, 0, stream>>>(q_w, kv_w, proj_w, whi, wlo);
    gemm_split<<<dim3(512), blk, 0, stream>>>(x, whi, wlo, 0, 3, 1,
                                              qb, ykvb, nullptr, nullptr);
    halo_attn<<<dim3(256, 8, 4), blk, 0, stream>>>(out, qb, ykvb, pt);
    gemm_split<<<dim3(512), blk, 0, stream>>>(out, whi, wlo, 384, 1, 0,
                                              nullptr, nullptr, out, proj_b);
}

// Round 18
// 94.378 us; speedup vs baseline: 1.2463x; 1.0041x over previous
//
#include <hip/hip_runtime.h>
#include <float.h>

// HaloAttn: x(4,128,128,128) f32 -> out(4,128,128,128) f32
// BS=8, HS=3, WIN=14, NH=8, DQK=DV=16, SCALE=0.25
//
// k0: conv_w      weights -> hi/lo bf16, frag-major W'[rb][kc][lr][8]
// k1: gemm_split  q=x@q_w^T, kv=x@kv_w^T -> ws bf16 head-major (split MFMA)
// k2: halo_attn   R18 = R17 + 2-deep ak prefetch pipeline (named-reg rotation)
// k3: gemm_split  d_out = d_out @ proj_w^T + proj_b (in place)
//
// Key space: g = wy*16+wx (wy<14, wx<16; wx>=14 or out-of-image = invalid).
// Permutation (pair m, sub-tile s, A-row i): key = 32m + (i>>2)*8 + 4s + (i&3).
// QK C-frag: lane(lr,cA) reg r holds S for key kb+4s+r, kb=32m+cA*8; those
// keys share window row wy=2m+(cA>>1), wx=(cA&1)*8+(4s+r) -> bias indices
// consecutive descending: bq[7-(4s+r)], bq walks -42/m (pointer-walk).
// Denominator: accs = mfma(valid8, pb, accs) -> every reg = masked sum.
// Invalid keys: bounded-garbage p (K<-pixel 0, guarded bias idx in [-2,440]),
// zeroed exactly by vbf (sum) and zeroed V^T rows (PV).
//
// Head-major ws: kv[8][65536][32] ushort @0 (32MB) | q[8][65536][16] @32M
//   | whi' @48M | wlo' (128KB each, frag-major).

typedef float f32x4 __attribute__((ext_vector_type(4)));
typedef short s16x4 __attribute__((ext_vector_type(4)));
typedef short s16x8 __attribute__((ext_vector_type(8)));
typedef unsigned int u32x2 __attribute__((ext_vector_type(2)));
typedef unsigned int u32x4 __attribute__((ext_vector_type(4)));

__device__ inline ushort f2bf(float f) {   // RNE float->bf16 (cold paths)
    unsigned u = __float_as_uint(f);
    return (ushort)((u + 0x7FFF + ((u >> 16) & 1)) >> 16);
}
__device__ inline float bf2f(ushort h) { return __uint_as_float((unsigned)h << 16); }
__device__ inline unsigned cvtpk(float a, float b) {   // D[15:0]=bf16(a), D[31:16]=bf16(b)
    unsigned r;
    asm("v_cvt_pk_bf16_f32 %0, %1, %2" : "=v"(r) : "v"(a), "v"(b));
    return r;
}
#if __has_builtin(__builtin_amdgcn_exp2f)
#define EXP2(x) __builtin_amdgcn_exp2f(x)
#else
#define EXP2(x) exp2f(x)
#endif

// ---------------------------------------------------------------------------
// Weight split into FRAG-MAJOR layout (rows 0-127 q_w, 128-383 kv_w, 384-511
// proj_w): W'[(row>>4)][col>>3][row&15][col&7].
__global__ __launch_bounds__(256) void conv_w(
    const float* __restrict__ q_w, const float* __restrict__ kv_w,
    const float* __restrict__ proj_w, ushort* whi, ushort* wlo)
{
    const int g = blockIdx.x * 256 + threadIdx.x;      // 0..65535
    const int row = g >> 7, col = g & 127;
    const float v = (row < 128) ? q_w[row * 128 + col]
                  : (row < 384) ? kv_w[(row - 128) * 128 + col]
                                : proj_w[(row - 384) * 128 + col];
    const ushort h = f2bf(v);
    const int off = ((row >> 4) * 2048) + ((col >> 3) * 128) + ((row & 15) * 8) + (col & 7);
    whi[off] = h;
    wlo[off] = f2bf(v - bf2f(h));
}

// ---------------------------------------------------------------------------
// Split-bf16 MFMA GEMM (unchanged, R13-proven).
__global__ __launch_bounds__(256) void gemm_split(
    const float* A,                                   // [M][128] fp32
    const ushort* __restrict__ Whi, const ushort* __restrict__ Wlo,
    int wbase, int ntc, int tok1,
    ushort* qb, ushort* kvb, float* outf, const float* __restrict__ bias)
{
    __shared__ ushort Ah[128 * 128];   // [row][k] swizzled 16B chunks, 32KB
    __shared__ ushort Al[128 * 128];

    const int t = threadIdx.x;
    const int row0 = blockIdx.x * 128;
    const int w = t >> 6, l = t & 63;
    const int wm = w >> 1, wn = w & 1;
    const int lr = l & 15, cA = l >> 4;

#pragma unroll
    for (int i = 0; i < 16; ++i) {
        const int idx = t + i * 256;
        const int p = idx >> 5, fc = idx & 31;         // row, float4-col
        const float4 v = *(const float4*)(A + (size_t)(row0 + p) * 128 + fc * 4);
        const int base = p * 128 + (((fc >> 1) ^ (p & 7)) << 3) + (fc & 1) * 4;
        const unsigned h01 = cvtpk(v.x, v.y), h23 = cvtpk(v.z, v.w);
        *(u32x2*)&Ah[base] = (u32x2){h01, h23};
        const float hx = __uint_as_float(h01 << 16);
        const float hy = __uint_as_float(h01 & 0xFFFF0000u);
        const float hz = __uint_as_float(h23 << 16);
        const float hw = __uint_as_float(h23 & 0xFFFF0000u);
        *(u32x2*)&Al[base] = (u32x2){ cvtpk(v.x - hx, v.y - hy),
                                      cvtpk(v.z - hz, v.w - hw) };
    }
    __syncthreads();

#pragma unroll 1
    for (int nt = 0; nt < ntc; ++nt) {
        f32x4 acc[4][4];
#pragma unroll
        for (int mf = 0; mf < 4; ++mf)
#pragma unroll
            for (int nf = 0; nf < 4; ++nf) acc[mf][nf] = (f32x4){0.f,0.f,0.f,0.f};

#pragma unroll 1
        for (int kk = 0; kk < 4; ++kk) {
            s16x8 wh[4], wl[4];
#pragma unroll
            for (int nf = 0; nf < 4; ++nf) {
                const int rb = (wbase >> 4) + nt * 8 + wn * 4 + nf;
                const size_t off = (size_t)rb * 2048 + (kk * 4 + cA) * 128 + lr * 8;
                wh[nf] = *(const s16x8*)&Whi[off];
                wl[nf] = *(const s16x8*)&Wlo[off];
            }
#pragma unroll
            for (int mf = 0; mf < 4; ++mf) {
                const int p = wm * 64 + mf * 16 + lr;
                const int off = p * 128 + ((((kk << 2) + cA) ^ (p & 7)) << 3);
                const s16x8 xh = *(const s16x8*)&Ah[off];
                const s16x8 xl = *(const s16x8*)&Al[off];
#pragma unroll
                for (int nf = 0; nf < 4; ++nf) {
                    acc[mf][nf] = __builtin_amdgcn_mfma_f32_16x16x32_bf16(
                                      wh[nf], xh, acc[mf][nf], 0, 0, 0);
                    acc[mf][nf] = __builtin_amdgcn_mfma_f32_16x16x32_bf16(
                                      wh[nf], xl, acc[mf][nf], 0, 0, 0);
                    acc[mf][nf] = __builtin_amdgcn_mfma_f32_16x16x32_bf16(
                                      wl[nf], xh, acc[mf][nf], 0, 0, 0);
                }
            }
        }

#pragma unroll
        for (int mf = 0; mf < 4; ++mf) {
            const size_t pix = row0 + wm * 64 + mf * 16 + lr;
#pragma unroll
            for (int nf = 0; nf < 4; ++nf) {
                const int chan = wn * 64 + nf * 16 + cA * 4;
                const f32x4 o = acc[mf][nf];
                if (tok1) {
                    const u32x2 pk = (u32x2){ cvtpk(o[0], o[1]), cvtpk(o[2], o[3]) };
                    if (nt == 0) {
                        const int head = wn * 4 + nf;
                        *(u32x2*)(qb + ((size_t)head << 20) + pix * 16 + (chan & 15)) = pk;
                    } else {
                        const int gchan = (nt - 1) * 128 + chan;
                        const int head = gchan >> 5;
                        *(u32x2*)(kvb + ((size_t)head << 21) + pix * 32 + (gchan & 31)) = pk;
                    }
                } else {
                    const float4 bv = *(const float4*)(bias + chan);
                    f32x4 r = o;
                    r[0] += bv.x; r[1] += bv.y; r[2] += bv.z; r[3] += bv.w;
                    *(f32x4*)(outf + pix * 128 + chan) = r;
                }
            }
        }
    }
}

// ---------------------------------------------------------------------------
// MFMA halo attention, R18. grid(256 spatial, 8 head, 4 batch), 256 thr =
// 4 waves = 4 q-tiles. ak gathers from global via keyoff LUT with a 2-DEEP
// software pipeline (named-register rotation; keyoff padded to 320).
__global__ __launch_bounds__(256) void halo_attn(
    float* out,                           // d_out fp32 (65536 x 128)
    const ushort* __restrict__ qg,        // ws q bf16 [8][65536][16] head-major
    const ushort* __restrict__ kvg,       // ws kv bf16 [8][65536][32] head-major
    const float* __restrict__ pos_table)  // (729, 8)
{
    __shared__ ushort VT[16][232];        // [dim][key] bf16
    __shared__ float  bias_l[444];        // logical idx -2..441 (2-entry guard)
    __shared__ int    keyoff[320];        // byte offset into kv slice (pad -> 0)
    __shared__ ushort vbf[232];           // valid ? bf16(1.0) : 0

    const int t  = threadIdx.x;
    const int bi = blockIdx.x, head = blockIdx.y, batch = blockIdx.z;
    const int by = bi >> 4, bx = bi & 15;
    const int w  = t >> 6;                 // wave id = q-tile
    const int l  = t & 63;
    const int lr = l & 15;
    const int cA = l >> 4;

    const char* kvh = (const char*)(kvg + ((size_t)head << 21) + ((size_t)batch << 19));

    // ---- per-block LUTs: key g = wy*16+wx (wy = g>>4, wx = g&15)
    if (t < 224) {
        const int wy = t >> 4, wx = t & 15;
        const int py = by * 8 + wy - 3, px = bx * 8 + wx - 3;
        const bool valid = (wx < 14) && ((unsigned)py < 128u) && ((unsigned)px < 128u);
        keyoff[t] = valid ? ((py * 128 + px) * 64) : 0;
        vbf[t]    = valid ? (ushort)0x3F80 : (ushort)0;
    } else {
        if (t < 232) vbf[t] = 0;
    }
    for (int i = 224 + t; i < 320; i += 256) keyoff[i] = 0;   // prefetch pad
    for (int i = t; i < 444; i += 256) {
        float v = 0.f;                     // guard entries (idx -2,-1) = 0 (bounded)
        if (i >= 2) {
            const int r = i - 2, ry = r / 21, rx = r - ry * 21;
            v = pos_table[((ry + 3) * 27 + rx + 3) * 8 + head] * 1.44269504f;
        }
        bias_l[i] = v;
    }
    __syncthreads();

    // ---- stage V^T (zeroed for invalid keys): threads 0..223, key t each
    if (t < 224) {
        const char* src = kvh + keyoff[t] + 32;        // v = d16..31 of record
        const bool valid = vbf[t] != 0;
        const s16x8 z = (s16x8){0,0,0,0,0,0,0,0};
        const s16x8 v0 = valid ? *(const s16x8*)src : z;
        const s16x8 v1 = valid ? *(const s16x8*)(src + 16) : z;
#pragma unroll
        for (int j = 0; j < 8; ++j) {
            VT[j][t]     = (ushort)v0[j];
            VT[j + 8][t] = (ushort)v1[j];
        }
    }
    __syncthreads();

    // ---- per-wave setup: q-tile = w
    const int gbase = ((lr >> 2) << 3) + (lr & 3);   // key-permutation base
    const int wy0 = cA >> 1, wx0 = (cA & 1) * 8;     // lane's m=0 window row/col
    const int q = w * 16 + lr;
    const int qy = q >> 3, qx = q & 7;
    const size_t pix = ((size_t)(batch * 128 + by * 8 + qy)) * 128 + bx * 8 + qx;
    float* optr = out + pix * 128 + head * 16 + cA * 4;
    // idx_min(m=0) = (qy+13-wy0)*21 + (qx+6-wx0); +2 guard offset
    const float* bptr = bias_l + 2 + (qy + 13 - wy0) * 21 + (qx + 6 - wx0);

    s16x8 qf;
#pragma unroll
    for (int k = 0; k < 8; ++k) qf[k] = 0;
    if (cA < 2)
        qf = *(const s16x8*)(qg + ((size_t)head << 20) + pix * 16 + cA * 8);

    f32x4 accv = (f32x4){0.f, 0.f, 0.f, 0.f};
    f32x4 accs = (f32x4){0.f, 0.f, 0.f, 0.f};

    // ---- 2-deep prefetch pipeline (named regs, rule-#20-safe rotation)
    s16x8 a0c = *(const s16x8*)(kvh + keyoff[gbase]      + cA * 16);
    s16x8 a1c = *(const s16x8*)(kvh + keyoff[gbase + 4]  + cA * 16);
    s16x8 a0n = *(const s16x8*)(kvh + keyoff[gbase + 32] + cA * 16);
    s16x8 a1n = *(const s16x8*)(kvh + keyoff[gbase + 36] + cA * 16);

#pragma unroll 1
    for (int m = 0; m < 7; ++m) {
        // issue loads for m+2 (keyoff padded to 320 -> always in-bounds)
        const int nx = 32 * (m + 2) + gbase;
        const s16x8 f0 = *(const s16x8*)(kvh + keyoff[nx]     + cA * 16);
        const s16x8 f1 = *(const s16x8*)(kvh + keyoff[nx + 4] + cA * 16);

        const int kb = 32 * m + cA * 8;                 // this lane's 8 keys
        const s16x8 vt  = *(const s16x8*)&VT[lr][kb];   // PV A-frag (dim=lr)
        const s16x8 vld = *(const s16x8*)&vbf[kb];      // sum A-frag (valid bf16)

        const f32x4 sf0 = __builtin_amdgcn_mfma_f32_16x16x32_bf16(
                              a0c, qf, (f32x4){0.f, 0.f, 0.f, 0.f}, 0, 0, 0);
        const f32x4 sf1 = __builtin_amdgcn_mfma_f32_16x16x32_bf16(
                              a1c, qf, (f32x4){0.f, 0.f, 0.f, 0.f}, 0, 0, 0);

        // bias: key kb+4s+r is window col wx0+4s+r -> bq[7-(4s+r)]
        const float* bq = bptr - m * 42;
        float pr0[4], pr1[4];
#pragma unroll
        for (int r = 0; r < 4; ++r)
            pr0[r] = EXP2(fmaf(sf0[r], 0.36067376f, bq[7 - r]));
#pragma unroll
        for (int r = 0; r < 4; ++r)
            pr1[r] = EXP2(fmaf(sf1[r], 0.36067376f, bq[3 - r]));

        const u32x4 pk = (u32x4){ cvtpk(pr0[0], pr0[1]), cvtpk(pr0[2], pr0[3]),
                                  cvtpk(pr1[0], pr1[1]), cvtpk(pr1[2], pr1[3]) };
        const s16x8 pb = *(const s16x8*)&pk;           // PV B-frag: keys kb..kb+7
        accv = __builtin_amdgcn_mfma_f32_16x16x32_bf16(vt,  pb, accv, 0, 0, 0);
        accs = __builtin_amdgcn_mfma_f32_16x16x32_bf16(vld, pb, accs, 0, 0, 0);

        a0c = a0n; a1c = a1n;              // rotate pipeline
        a0n = f0;  a1n = f1;
    }

    // ---- normalize: every accs reg = full masked sum for q = w*16+lr
    const float inv = 1.0f / accs[0];
    *(f32x4*)optr = accv * inv;
}

// ---------------------------------------------------------------------------
extern "C" void kernel_launch(void* const* d_in, const int* in_sizes, int n_in,
                              void* d_out, int out_size, void* d_ws, size_t ws_size,
                              hipStream_t stream) {
    const float* x      = (const float*)d_in[0];
    const float* q_w    = (const float*)d_in[1];
    const float* kv_w   = (const float*)d_in[2];
    const float* pt     = (const float*)d_in[3];
    const float* proj_w = (const float*)d_in[4];
    const float* proj_b = (const float*)d_in[5];
    float* out = (float*)d_out;

    ushort* ykvb = (ushort*)d_ws;                                   // 32 MB head-major
    ushort* qb   = (ushort*)((char*)d_ws + 33554432);               // 16 MB head-major
    ushort* whi  = (ushort*)((char*)d_ws + 33554432 + 16777216);    // 128 KB frag-major
    ushort* wlo  = whi + 65536;                                     // 128 KB

    const dim3 blk(256);
    conv_w<<<dim3(256), blk, 0, stream>>>(q_w, kv_w, proj_w, whi, wlo);
    gemm_split<<<dim3(512), blk, 0, stream>>>(x, whi, wlo, 0, 3, 1,
                                              qb, ykvb, nullptr, nullptr);
    halo_attn<<<dim3(256, 8, 4), blk, 0, stream>>>(out, qb, ykvb, pt);
    gemm_split<<<dim3(512), blk, 0, stream>>>(out, whi, wlo, 384, 1, 0,
                                              nullptr, nullptr, out, proj_b);
}

// Round 19
// 90.607 us; speedup vs baseline: 1.2982x; 1.0416x over previous
//
#include <hip/hip_runtime.h>
#include <float.h>

// HaloAttn: x(4,128,128,128) f32 -> out(4,128,128,128) f32
// BS=8, HS=3, WIN=14, NH=8, DQK=DV=16, SCALE=0.25
//
// k0: conv_w      weights -> hi/lo bf16, frag-major W'[rb][kc][lr][8]
// k1: gemm_split  q=x@q_w^T, kv=x@kv_w^T -> ws bf16 head-major (split MFMA)
// k2: halo_attn   R19 = R17 VALU-diet inner loop + R13 geometry:
//                 2 batches/block (z=2), wave=(batch,q-half), 2 q-tiles/wave
//                 -> prologue amortized 2x, ak gathers per q halved.
// k3: gemm_split  d_out = d_out @ proj_w^T + proj_b (in place)
//
// Key space: g = wy*16+wx (wy<14, wx<16; wx>=14 or out-of-image = invalid).
// Permutation (pair m, sub-tile s, A-row i): key = 32m + (i>>2)*8 + 4s + (i&3).
// QK C-frag: lane(lr,cA) reg r holds S for key kb+4s+r, kb=32m+cA*8; those
// keys share window row wy=2m+(cA>>1), wx=(cA&1)*8+(4s+r) -> bias indices
// consecutive descending: bq[7-(4s+r)], bq walks -42/m (pointer-walk).
// Denominator: accs = mfma(valid8, pb, accs) -> every reg = masked sum.
// Invalid keys: bounded-garbage p (K<-pixel 0, guarded bias idx in [-2,440]),
// zeroed exactly by vbf (sum) and zeroed V^T rows (PV).
//
// Head-major ws: kv[8][65536][32] ushort @0 (32MB) | q[8][65536][16] @32M
//   | whi' @48M | wlo' (128KB each, frag-major).

typedef float f32x4 __attribute__((ext_vector_type(4)));
typedef short s16x4 __attribute__((ext_vector_type(4)));
typedef short s16x8 __attribute__((ext_vector_type(8)));
typedef unsigned int u32x2 __attribute__((ext_vector_type(2)));
typedef unsigned int u32x4 __attribute__((ext_vector_type(4)));

__device__ inline ushort f2bf(float f) {   // RNE float->bf16 (cold paths)
    unsigned u = __float_as_uint(f);
    return (ushort)((u + 0x7FFF + ((u >> 16) & 1)) >> 16);
}
__device__ inline float bf2f(ushort h) { return __uint_as_float((unsigned)h << 16); }
__device__ inline unsigned cvtpk(float a, float b) {   // D[15:0]=bf16(a), D[31:16]=bf16(b)
    unsigned r;
    asm("v_cvt_pk_bf16_f32 %0, %1, %2" : "=v"(r) : "v"(a), "v"(b));
    return r;
}
#if __has_builtin(__builtin_amdgcn_exp2f)
#define EXP2(x) __builtin_amdgcn_exp2f(x)
#else
#define EXP2(x) exp2f(x)
#endif

// ---------------------------------------------------------------------------
// Weight split into FRAG-MAJOR layout (rows 0-127 q_w, 128-383 kv_w, 384-511
// proj_w): W'[(row>>4)][col>>3][row&15][col&7].
__global__ __launch_bounds__(256) void conv_w(
    const float* __restrict__ q_w, const float* __restrict__ kv_w,
    const float* __restrict__ proj_w, ushort* whi, ushort* wlo)
{
    const int g = blockIdx.x * 256 + threadIdx.x;      // 0..65535
    const int row = g >> 7, col = g & 127;
    const float v = (row < 128) ? q_w[row * 128 + col]
                  : (row < 384) ? kv_w[(row - 128) * 128 + col]
                                : proj_w[(row - 384) * 128 + col];
    const ushort h = f2bf(v);
    const int off = ((row >> 4) * 2048) + ((col >> 3) * 128) + ((row & 15) * 8) + (col & 7);
    whi[off] = h;
    wlo[off] = f2bf(v - bf2f(h));
}

// ---------------------------------------------------------------------------
// Split-bf16 MFMA GEMM (unchanged, R13-proven).
__global__ __launch_bounds__(256) void gemm_split(
    const float* A,                                   // [M][128] fp32
    const ushort* __restrict__ Whi, const ushort* __restrict__ Wlo,
    int wbase, int ntc, int tok1,
    ushort* qb, ushort* kvb, float* outf, const float* __restrict__ bias)
{
    __shared__ ushort Ah[128 * 128];   // [row][k] swizzled 16B chunks, 32KB
    __shared__ ushort Al[128 * 128];

    const int t = threadIdx.x;
    const int row0 = blockIdx.x * 128;
    const int w = t >> 6, l = t & 63;
    const int wm = w >> 1, wn = w & 1;
    const int lr = l & 15, cA = l >> 4;

#pragma unroll
    for (int i = 0; i < 16; ++i) {
        const int idx = t + i * 256;
        const int p = idx >> 5, fc = idx & 31;         // row, float4-col
        const float4 v = *(const float4*)(A + (size_t)(row0 + p) * 128 + fc * 4);
        const int base = p * 128 + (((fc >> 1) ^ (p & 7)) << 3) + (fc & 1) * 4;
        const unsigned h01 = cvtpk(v.x, v.y), h23 = cvtpk(v.z, v.w);
        *(u32x2*)&Ah[base] = (u32x2){h01, h23};
        const float hx = __uint_as_float(h01 << 16);
        const float hy = __uint_as_float(h01 & 0xFFFF0000u);
        const float hz = __uint_as_float(h23 << 16);
        const float hw = __uint_as_float(h23 & 0xFFFF0000u);
        *(u32x2*)&Al[base] = (u32x2){ cvtpk(v.x - hx, v.y - hy),
                                      cvtpk(v.z - hz, v.w - hw) };
    }
    __syncthreads();

#pragma unroll 1
    for (int nt = 0; nt < ntc; ++nt) {
        f32x4 acc[4][4];
#pragma unroll
        for (int mf = 0; mf < 4; ++mf)
#pragma unroll
            for (int nf = 0; nf < 4; ++nf) acc[mf][nf] = (f32x4){0.f,0.f,0.f,0.f};

#pragma unroll 1
        for (int kk = 0; kk < 4; ++kk) {
            s16x8 wh[4], wl[4];
#pragma unroll
            for (int nf = 0; nf < 4; ++nf) {
                const int rb = (wbase >> 4) + nt * 8 + wn * 4 + nf;
                const size_t off = (size_t)rb * 2048 + (kk * 4 + cA) * 128 + lr * 8;
                wh[nf] = *(const s16x8*)&Whi[off];
                wl[nf] = *(const s16x8*)&Wlo[off];
            }
#pragma unroll
            for (int mf = 0; mf < 4; ++mf) {
                const int p = wm * 64 + mf * 16 + lr;
                const int off = p * 128 + ((((kk << 2) + cA) ^ (p & 7)) << 3);
                const s16x8 xh = *(const s16x8*)&Ah[off];
                const s16x8 xl = *(const s16x8*)&Al[off];
#pragma unroll
                for (int nf = 0; nf < 4; ++nf) {
                    acc[mf][nf] = __builtin_amdgcn_mfma_f32_16x16x32_bf16(
                                      wh[nf], xh, acc[mf][nf], 0, 0, 0);
                    acc[mf][nf] = __builtin_amdgcn_mfma_f32_16x16x32_bf16(
                                      wh[nf], xl, acc[mf][nf], 0, 0, 0);
                    acc[mf][nf] = __builtin_amdgcn_mfma_f32_16x16x32_bf16(
                                      wl[nf], xh, acc[mf][nf], 0, 0, 0);
                }
            }
        }

#pragma unroll
        for (int mf = 0; mf < 4; ++mf) {
            const size_t pix = row0 + wm * 64 + mf * 16 + lr;
#pragma unroll
            for (int nf = 0; nf < 4; ++nf) {
                const int chan = wn * 64 + nf * 16 + cA * 4;
                const f32x4 o = acc[mf][nf];
                if (tok1) {
                    const u32x2 pk = (u32x2){ cvtpk(o[0], o[1]), cvtpk(o[2], o[3]) };
                    if (nt == 0) {
                        const int head = wn * 4 + nf;
                        *(u32x2*)(qb + ((size_t)head << 20) + pix * 16 + (chan & 15)) = pk;
                    } else {
                        const int gchan = (nt - 1) * 128 + chan;
                        const int head = gchan >> 5;
                        *(u32x2*)(kvb + ((size_t)head << 21) + pix * 32 + (gchan & 31)) = pk;
                    }
                } else {
                    const float4 bv = *(const float4*)(bias + chan);
                    f32x4 r = o;
                    r[0] += bv.x; r[1] += bv.y; r[2] += bv.z; r[3] += bv.w;
                    *(f32x4*)(outf + pix * 128 + chan) = r;
                }
            }
        }
    }
}

// ---------------------------------------------------------------------------
// MFMA halo attention, R19. grid(256 spatial, 8 head, 2 batch-pair), 256 thr
// = 4 waves = 2 batches x 2 q-halves; wave owns 2 q-tiles sharing ak loads.
__global__ __launch_bounds__(256) void halo_attn(
    float* out,                           // d_out fp32 (65536 x 128)
    const ushort* __restrict__ qg,        // ws q bf16 [8][65536][16] head-major
    const ushort* __restrict__ kvg,       // ws kv bf16 [8][65536][32] head-major
    const float* __restrict__ pos_table)  // (729, 8)
{
    __shared__ ushort VT[2][16][232];     // [local batch][dim][key]   14848 B
    __shared__ float  bias_l[444];        // logical idx -2..441 (2-entry guard)
    __shared__ int    keyoff[256];        // byte offset into kv slice (pad -> 0)
    __shared__ ushort vbf[232];           // valid ? bf16(1.0) : 0

    const int t  = threadIdx.x;
    const int bi = blockIdx.x, head = blockIdx.y, bpair = blockIdx.z;
    const int by = bi >> 4, bx = bi & 15;
    const int w  = t >> 6;
    const int lb = w >> 1;                 // local batch 0/1
    const int qh = w & 1;                  // q-half
    const int batch = bpair * 2 + lb;
    const int l  = t & 63;
    const int lr = l & 15;
    const int cA = l >> 4;

    const char* kvh = (const char*)(kvg + ((size_t)head << 21) + ((size_t)batch << 19));

    // ---- per-block LUTs: key g = wy*16+wx (wy = g>>4, wx = g&15)
    if (t < 224) {
        const int wy = t >> 4, wx = t & 15;
        const int py = by * 8 + wy - 3, px = bx * 8 + wx - 3;
        const bool valid = (wx < 14) && ((unsigned)py < 128u) && ((unsigned)px < 128u);
        keyoff[t] = valid ? ((py * 128 + px) * 64) : 0;
        vbf[t]    = valid ? (ushort)0x3F80 : (ushort)0;
    } else {
        keyoff[t] = 0;                     // prefetch pad
        if (t < 232) vbf[t] = 0;
    }
    for (int i = t; i < 444; i += 256) {
        float v = 0.f;                     // guard entries (idx -2,-1) = 0 (bounded)
        if (i >= 2) {
            const int r = i - 2, ry = r / 21, rx = r - ry * 21;
            v = pos_table[((ry + 3) * 27 + rx + 3) * 8 + head] * 1.44269504f;
        }
        bias_l[i] = v;
    }
    __syncthreads();

    // ---- stage V^T for BOTH batches (448 items over 256 threads)
#pragma unroll
    for (int it = 0; it < 2; ++it) {
        const int idx = t + it * 256;
        if (idx < 448) {
            const int slb = (idx < 224) ? 0 : 1;       // staged local batch
            const int key = idx - slb * 224;
            const char* sb = (const char*)(kvg + ((size_t)head << 21)
                             + ((size_t)(bpair * 2 + slb) << 19));
            const char* src = sb + keyoff[key] + 32;   // v = d16..31 of record
            const bool valid = vbf[key] != 0;
            const s16x8 z = (s16x8){0,0,0,0,0,0,0,0};
            const s16x8 v0 = valid ? *(const s16x8*)src : z;
            const s16x8 v1 = valid ? *(const s16x8*)(src + 16) : z;
#pragma unroll
            for (int j = 0; j < 8; ++j) {
                VT[slb][j][key]     = (ushort)v0[j];
                VT[slb][j + 8][key] = (ushort)v1[j];
            }
        }
    }
    __syncthreads();

    // ---- per-wave setup: 2 q-tiles (qt = qh*2 + j)
    const int gbase = ((lr >> 2) << 3) + (lr & 3);   // key-permutation base
    const int wy0 = cA >> 1, wx0 = (cA & 1) * 8;     // lane's m=0 window row/col
    const ushort* qhp = qg + ((size_t)head << 20);
    s16x8 qf[2];
    float* optr[2];
    const float* bptr[2];
#pragma unroll
    for (int j = 0; j < 2; ++j) {
        const int q = (qh * 2 + j) * 16 + lr;
        const int qy = q >> 3, qx = q & 7;
        const size_t pix = ((size_t)(batch * 128 + by * 8 + qy)) * 128 + bx * 8 + qx;
        optr[j] = out + pix * 128 + head * 16 + cA * 4;
        // idx_min(m=0) = (qy+13-wy0)*21 + (qx+6-wx0); +2 guard offset
        bptr[j] = bias_l + 2 + (qy + 13 - wy0) * 21 + (qx + 6 - wx0);
#pragma unroll
        for (int k = 0; k < 8; ++k) qf[j][k] = 0;
        if (cA < 2)
            qf[j] = *(const s16x8*)(qhp + pix * 16 + cA * 8);
    }

    f32x4 accv[2], accs[2];
#pragma unroll
    for (int j = 0; j < 2; ++j) {
        accv[j] = (f32x4){0.f, 0.f, 0.f, 0.f};
        accs[j] = (f32x4){0.f, 0.f, 0.f, 0.f};
    }

    // prefetch pair 0 (invalid keys read pixel 0 -> bounded garbage, zeroed later)
    s16x8 ak0 = *(const s16x8*)(kvh + keyoff[gbase]     + cA * 16);
    s16x8 ak1 = *(const s16x8*)(kvh + keyoff[gbase + 4] + cA * 16);

#pragma unroll 1
    for (int m = 0; m < 7; ++m) {
        const int nx = 32 * (m + 1) + gbase;           // keyoff padded -> in-bounds
        const s16x8 nk0 = *(const s16x8*)(kvh + keyoff[nx]     + cA * 16);
        const s16x8 nk1 = *(const s16x8*)(kvh + keyoff[nx + 4] + cA * 16);

        const int kb = 32 * m + cA * 8;                 // this lane's 8 keys
        const s16x8 vt  = *(const s16x8*)&VT[lb][lr][kb];  // PV A-frag (dim=lr)
        const s16x8 vld = *(const s16x8*)&vbf[kb];         // sum A-frag

#pragma unroll
        for (int j = 0; j < 2; ++j) {
            const f32x4 sf0 = __builtin_amdgcn_mfma_f32_16x16x32_bf16(
                                  ak0, qf[j], (f32x4){0.f, 0.f, 0.f, 0.f}, 0, 0, 0);
            const f32x4 sf1 = __builtin_amdgcn_mfma_f32_16x16x32_bf16(
                                  ak1, qf[j], (f32x4){0.f, 0.f, 0.f, 0.f}, 0, 0, 0);
            // bias: key kb+4s+r is window col wx0+4s+r -> bq[7-(4s+r)]
            const float* bq = bptr[j] - m * 42;
            float pr0[4], pr1[4];
#pragma unroll
            for (int r = 0; r < 4; ++r)
                pr0[r] = EXP2(fmaf(sf0[r], 0.36067376f, bq[7 - r]));
#pragma unroll
            for (int r = 0; r < 4; ++r)
                pr1[r] = EXP2(fmaf(sf1[r], 0.36067376f, bq[3 - r]));

            const u32x4 pk = (u32x4){ cvtpk(pr0[0], pr0[1]), cvtpk(pr0[2], pr0[3]),
                                      cvtpk(pr1[0], pr1[1]), cvtpk(pr1[2], pr1[3]) };
            const s16x8 pb = *(const s16x8*)&pk;       // PV B-frag: keys kb..kb+7
            accv[j] = __builtin_amdgcn_mfma_f32_16x16x32_bf16(vt,  pb, accv[j], 0, 0, 0);
            accs[j] = __builtin_amdgcn_mfma_f32_16x16x32_bf16(vld, pb, accs[j], 0, 0, 0);
        }
        ak0 = nk0;
        ak1 = nk1;
    }

    // ---- normalize: every accs reg = full masked sum
#pragma unroll
    for (int j = 0; j < 2; ++j) {
        const float inv = 1.0f / accs[j][0];
        *(f32x4*)optr[j] = accv[j] * inv;
    }
}

// ---------------------------------------------------------------------------
extern "C" void kernel_launch(void* const* d_in, const int* in_sizes, int n_in,
                              void* d_out, int out_size, void* d_ws, size_t ws_size,
                              hipStream_t stream) {
    const float* x      = (const float*)d_in[0];
    const float* q_w    = (const float*)d_in[1];
    const float* kv_w   = (const float*)d_in[2];
    const float* pt     = (const float*)d_in[3];
    const float* proj_w = (const float*)d_in[4];
    const float* proj_b = (const float*)d_in[5];
    float* out = (float*)d_out;

    ushort* ykvb = (ushort*)d_ws;                                   // 32 MB head-major
    ushort* qb   = (ushort*)((char*)d_ws + 33554432);               // 16 MB head-major
    ushort* whi  = (ushort*)((char*)d_ws + 33554432 + 16777216);    // 128 KB frag-major
    ushort* wlo  = whi + 65536;                                     // 128 KB

    const dim3 blk(256);
    conv_w<<<dim3(256), blk, 0, stream>>>(q_w, kv_w, proj_w, whi, wlo);
    gemm_split<<<dim3(512), blk, 0, stream>>>(x, whi, wlo, 0, 3, 1,
                                              qb, ykvb, nullptr, nullptr);
    halo_attn<<<dim3(256, 8, 2), blk, 0, stream>>>(out, qb, ykvb, pt);
    gemm_split<<<dim3(512), blk, 0, stream>>>(out, whi, wlo, 384, 1, 0,
                                              nullptr, nullptr, out, proj_b);
}

// Round 21
// 88.163 us; speedup vs baseline: 1.3341x; 1.0277x over previous
//
#include <hip/hip_runtime.h>
#include <float.h>

// HaloAttn: x(4,128,128,128) f32 -> out(4,128,128,128) f32
// BS=8, HS=3, WIN=14, NH=8, DQK=DV=16, SCALE=0.25
//
// k0: conv_w      weights -> hi/lo bf16 frag-major + PRECOMPUTED bias_g[8][448]
// k1: gemm_split  q=x@q_w^T, kv=x@kv_w^T -> ws bf16 head-major (split MFMA)
// k2: halo_attn   R21 (=R20 + bias staging coverage fix): 512-thr blocks
//                 (4 batches x 2 q-halves), LUT/bias amortized over 4 batches.
// k3: gemm_split  d_out = d_out @ proj_w^T + proj_b (in place)
//
// R20 bug: bias_l[448] staged only by threads 256..511 -> entries 256..447
// uninitialized. R21 stages with a full-coverage strided loop.
//
// Key space: g = wy*16+wx (wy<14, wx<16; wx>=14 or out-of-image = invalid).
// Permutation (pair m, sub-tile s, A-row i): key = 32m + (i>>2)*8 + 4s + (i&3).
// QK C-frag: lane(lr,cA) reg r holds S for key kb+4s+r, kb=32m+cA*8; those
// keys share window row wy=2m+(cA>>1), wx=(cA&1)*8+(4s+r) -> bias indices
// consecutive descending: bq[7-(4s+r)], bq walks -42/m (pointer-walk).
// Denominator: accs = mfma(valid8, pb, accs) -> every reg = masked sum.
// Invalid keys: bounded-garbage p (K<-pixel 0, guarded bias idx), zeroed
// exactly by vbf (sum) and zeroed V^T rows (PV).
//
// ws: kv[8][65536][32] u16 @0 (32MB) | q[8][65536][16] @32M (16MB)
//   | whi' @48M (128KB) | wlo' (128KB) | bias_g[8][448] f32 (14KB).

typedef float f32x4 __attribute__((ext_vector_type(4)));
typedef short s16x4 __attribute__((ext_vector_type(4)));
typedef short s16x8 __attribute__((ext_vector_type(8)));
typedef unsigned int u32x2 __attribute__((ext_vector_type(2)));
typedef unsigned int u32x4 __attribute__((ext_vector_type(4)));

__device__ inline ushort f2bf(float f) {   // RNE float->bf16 (cold paths)
    unsigned u = __float_as_uint(f);
    return (ushort)((u + 0x7FFF + ((u >> 16) & 1)) >> 16);
}
__device__ inline float bf2f(ushort h) { return __uint_as_float((unsigned)h << 16); }
__device__ inline unsigned cvtpk(float a, float b) {   // D[15:0]=bf16(a), D[31:16]=bf16(b)
    unsigned r;
    asm("v_cvt_pk_bf16_f32 %0, %1, %2" : "=v"(r) : "v"(a), "v"(b));
    return r;
}
#if __has_builtin(__builtin_amdgcn_exp2f)
#define EXP2(x) __builtin_amdgcn_exp2f(x)
#else
#define EXP2(x) exp2f(x)
#endif

// ---------------------------------------------------------------------------
// Weight split (frag-major) + bias table precompute.
__global__ __launch_bounds__(256) void conv_w(
    const float* __restrict__ q_w, const float* __restrict__ kv_w,
    const float* __restrict__ proj_w, const float* __restrict__ pos_table,
    ushort* whi, ushort* wlo, float* bias_g)
{
    if (blockIdx.x < 256) {
        const int g = blockIdx.x * 256 + threadIdx.x;      // 0..65535
        const int row = g >> 7, col = g & 127;
        const float v = (row < 128) ? q_w[row * 128 + col]
                      : (row < 384) ? kv_w[(row - 128) * 128 + col]
                                    : proj_w[(row - 384) * 128 + col];
        const ushort h = f2bf(v);
        const int off = ((row >> 4) * 2048) + ((col >> 3) * 128)
                      + ((row & 15) * 8) + (col & 7);
        whi[off] = h;
        wlo[off] = f2bf(v - bf2f(h));
    } else {
        const int i = (blockIdx.x - 256) * 256 + threadIdx.x;  // 0..3583
        if (i < 8 * 448) {
            const int h = i / 448, e = i - h * 448;
            float v = 0.f;
            if (e >= 2) {                  // logical rel-idx r = e-2 (bounded pad)
                const int r = e - 2, ry = r / 21, rx = r - ry * 21;
                v = pos_table[((ry + 3) * 27 + rx + 3) * 8 + h] * 1.44269504f;
            }
            bias_g[h * 448 + e] = v;
        }
    }
}

// ---------------------------------------------------------------------------
// Split-bf16 MFMA GEMM (unchanged, R13-proven).
__global__ __launch_bounds__(256) void gemm_split(
    const float* A,                                   // [M][128] fp32
    const ushort* __restrict__ Whi, const ushort* __restrict__ Wlo,
    int wbase, int ntc, int tok1,
    ushort* qb, ushort* kvb, float* outf, const float* __restrict__ bias)
{
    __shared__ ushort Ah[128 * 128];   // [row][k] swizzled 16B chunks, 32KB
    __shared__ ushort Al[128 * 128];

    const int t = threadIdx.x;
    const int row0 = blockIdx.x * 128;
    const int w = t >> 6, l = t & 63;
    const int wm = w >> 1, wn = w & 1;
    const int lr = l & 15, cA = l >> 4;

#pragma unroll
    for (int i = 0; i < 16; ++i) {
        const int idx = t + i * 256;
        const int p = idx >> 5, fc = idx & 31;         // row, float4-col
        const float4 v = *(const float4*)(A + (size_t)(row0 + p) * 128 + fc * 4);
        const int base = p * 128 + (((fc >> 1) ^ (p & 7)) << 3) + (fc & 1) * 4;
        const unsigned h01 = cvtpk(v.x, v.y), h23 = cvtpk(v.z, v.w);
        *(u32x2*)&Ah[base] = (u32x2){h01, h23};
        const float hx = __uint_as_float(h01 << 16);
        const float hy = __uint_as_float(h01 & 0xFFFF0000u);
        const float hz = __uint_as_float(h23 << 16);
        const float hw = __uint_as_float(h23 & 0xFFFF0000u);
        *(u32x2*)&Al[base] = (u32x2){ cvtpk(v.x - hx, v.y - hy),
                                      cvtpk(v.z - hz, v.w - hw) };
    }
    __syncthreads();

#pragma unroll 1
    for (int nt = 0; nt < ntc; ++nt) {
        f32x4 acc[4][4];
#pragma unroll
        for (int mf = 0; mf < 4; ++mf)
#pragma unroll
            for (int nf = 0; nf < 4; ++nf) acc[mf][nf] = (f32x4){0.f,0.f,0.f,0.f};

#pragma unroll 1
        for (int kk = 0; kk < 4; ++kk) {
            s16x8 wh[4], wl[4];
#pragma unroll
            for (int nf = 0; nf < 4; ++nf) {
                const int rb = (wbase >> 4) + nt * 8 + wn * 4 + nf;
                const size_t off = (size_t)rb * 2048 + (kk * 4 + cA) * 128 + lr * 8;
                wh[nf] = *(const s16x8*)&Whi[off];
                wl[nf] = *(const s16x8*)&Wlo[off];
            }
#pragma unroll
            for (int mf = 0; mf < 4; ++mf) {
                const int p = wm * 64 + mf * 16 + lr;
                const int off = p * 128 + ((((kk << 2) + cA) ^ (p & 7)) << 3);
                const s16x8 xh = *(const s16x8*)&Ah[off];
                const s16x8 xl = *(const s16x8*)&Al[off];
#pragma unroll
                for (int nf = 0; nf < 4; ++nf) {
                    acc[mf][nf] = __builtin_amdgcn_mfma_f32_16x16x32_bf16(
                                      wh[nf], xh, acc[mf][nf], 0, 0, 0);
                    acc[mf][nf] = __builtin_amdgcn_mfma_f32_16x16x32_bf16(
                                      wh[nf], xl, acc[mf][nf], 0, 0, 0);
                    acc[mf][nf] = __builtin_amdgcn_mfma_f32_16x16x32_bf16(
                                      wl[nf], xh, acc[mf][nf], 0, 0, 0);
                }
            }
        }

#pragma unroll
        for (int mf = 0; mf < 4; ++mf) {
            const size_t pix = row0 + wm * 64 + mf * 16 + lr;
#pragma unroll
            for (int nf = 0; nf < 4; ++nf) {
                const int chan = wn * 64 + nf * 16 + cA * 4;
                const f32x4 o = acc[mf][nf];
                if (tok1) {
                    const u32x2 pk = (u32x2){ cvtpk(o[0], o[1]), cvtpk(o[2], o[3]) };
                    if (nt == 0) {
                        const int head = wn * 4 + nf;
                        *(u32x2*)(qb + ((size_t)head << 20) + pix * 16 + (chan & 15)) = pk;
                    } else {
                        const int gchan = (nt - 1) * 128 + chan;
                        const int head = gchan >> 5;
                        *(u32x2*)(kvb + ((size_t)head << 21) + pix * 32 + (gchan & 31)) = pk;
                    }
                } else {
                    const float4 bv = *(const float4*)(bias + chan);
                    f32x4 r = o;
                    r[0] += bv.x; r[1] += bv.y; r[2] += bv.z; r[3] += bv.w;
                    *(f32x4*)(outf + pix * 128 + chan) = r;
                }
            }
        }
    }
}

// ---------------------------------------------------------------------------
// MFMA halo attention, R21. grid(256 spatial, 8 head), 512 thr = 8 waves =
// 4 batches x 2 q-halves. bias_l staged by full-coverage strided copy.
__global__ __launch_bounds__(512) void halo_attn(
    float* out,                           // d_out fp32 (65536 x 128)
    const ushort* __restrict__ qg,        // ws q bf16 [8][65536][16] head-major
    const ushort* __restrict__ kvg,       // ws kv bf16 [8][65536][32] head-major
    const float* __restrict__ bias_g)     // ws bias [8][448] (pre-scaled log2e)
{
    __shared__ ushort VT[4][16][232];     // [batch][dim][key]        29696 B
    __shared__ float  bias_l[448];        // idx -2..445 (2-entry guard)
    __shared__ int    keyoff[256];        // byte offset into kv slice (pad -> 0)
    __shared__ ushort vbf[232];           // valid ? bf16(1.0) : 0

    const int t  = threadIdx.x;
    const int bi = blockIdx.x, head = blockIdx.y;
    const int by = bi >> 4, bx = bi & 15;
    const int w  = t >> 6;
    const int lb = w >> 1;                 // batch 0..3
    const int qh = w & 1;                  // q-half
    const int l  = t & 63;
    const int lr = l & 15;
    const int cA = l >> 4;

    const char* kvh = (const char*)(kvg + ((size_t)head << 21) + ((size_t)lb << 19));

    // ---- per-block LUTs: key g = wy*16+wx (wy = g>>4, wx = g&15)
    if (t < 224) {
        const int wy = t >> 4, wx = t & 15;
        const int py = by * 8 + wy - 3, px = bx * 8 + wx - 3;
        const bool valid = (wx < 14) && ((unsigned)py < 128u) && ((unsigned)px < 128u);
        keyoff[t] = valid ? ((py * 128 + px) * 64) : 0;
        vbf[t]    = valid ? (ushort)0x3F80 : (ushort)0;
    } else if (t < 256) {
        keyoff[t] = 0;                     // prefetch pad
        if (t < 232) vbf[t] = 0;
    }
    for (int i = t; i < 448; i += 512)     // FULL-coverage bias copy (R20 fix)
        bias_l[i] = bias_g[head * 448 + i];
    __syncthreads();

    // ---- stage V^T for all 4 batches: 2 rounds, slb = t>>7, key = (t&127)+128*rd
#pragma unroll
    for (int rd = 0; rd < 2; ++rd) {
        const int key = (t & 127) + rd * 128;
        const int slb = t >> 7;            // 0..3
        if (key < 224) {
            const char* sb = (const char*)(kvg + ((size_t)head << 21)
                             + ((size_t)slb << 19));
            const char* src = sb + keyoff[key] + 32;   // v = d16..31 of record
            const bool valid = vbf[key] != 0;
            const s16x8 z = (s16x8){0,0,0,0,0,0,0,0};
            const s16x8 v0 = valid ? *(const s16x8*)src : z;
            const s16x8 v1 = valid ? *(const s16x8*)(src + 16) : z;
#pragma unroll
            for (int j = 0; j < 8; ++j) {
                VT[slb][j][key]     = (ushort)v0[j];
                VT[slb][j + 8][key] = (ushort)v1[j];
            }
        }
    }
    __syncthreads();

    // ---- per-wave setup: 2 q-tiles (qt = qh*2 + j), batch = lb
    const int gbase = ((lr >> 2) << 3) + (lr & 3);   // key-permutation base
    const int wy0 = cA >> 1, wx0 = (cA & 1) * 8;     // lane's m=0 window row/col
    const ushort* qhp = qg + ((size_t)head << 20);
    s16x8 qf[2];
    float* optr[2];
    const float* bptr[2];
#pragma unroll
    for (int j = 0; j < 2; ++j) {
        const int q = (qh * 2 + j) * 16 + lr;
        const int qy = q >> 3, qx = q & 7;
        const size_t pix = ((size_t)(lb * 128 + by * 8 + qy)) * 128 + bx * 8 + qx;
        optr[j] = out + pix * 128 + head * 16 + cA * 4;
        // idx_min(m=0) = (qy+13-wy0)*21 + (qx+6-wx0); +2 guard offset
        bptr[j] = bias_l + 2 + (qy + 13 - wy0) * 21 + (qx + 6 - wx0);
#pragma unroll
        for (int k = 0; k < 8; ++k) qf[j][k] = 0;
        if (cA < 2)
            qf[j] = *(const s16x8*)(qhp + pix * 16 + cA * 8);
    }

    f32x4 accv[2], accs[2];
#pragma unroll
    for (int j = 0; j < 2; ++j) {
        accv[j] = (f32x4){0.f, 0.f, 0.f, 0.f};
        accs[j] = (f32x4){0.f, 0.f, 0.f, 0.f};
    }

    // prefetch pair 0 (invalid keys read pixel 0 -> bounded garbage, zeroed later)
    s16x8 ak0 = *(const s16x8*)(kvh + keyoff[gbase]     + cA * 16);
    s16x8 ak1 = *(const s16x8*)(kvh + keyoff[gbase + 4] + cA * 16);

#pragma unroll 1
    for (int m = 0; m < 7; ++m) {
        const int nx = 32 * (m + 1) + gbase;           // keyoff padded -> in-bounds
        const s16x8 nk0 = *(const s16x8*)(kvh + keyoff[nx]     + cA * 16);
        const s16x8 nk1 = *(const s16x8*)(kvh + keyoff[nx + 4] + cA * 16);

        const int kb = 32 * m + cA * 8;                 // this lane's 8 keys
        const s16x8 vt  = *(const s16x8*)&VT[lb][lr][kb];  // PV A-frag (dim=lr)
        const s16x8 vld = *(const s16x8*)&vbf[kb];         // sum A-frag

#pragma unroll
        for (int j = 0; j < 2; ++j) {
            const f32x4 sf0 = __builtin_amdgcn_mfma_f32_16x16x32_bf16(
                                  ak0, qf[j], (f32x4){0.f, 0.f, 0.f, 0.f}, 0, 0, 0);
            const f32x4 sf1 = __builtin_amdgcn_mfma_f32_16x16x32_bf16(
                                  ak1, qf[j], (f32x4){0.f, 0.f, 0.f, 0.f}, 0, 0, 0);
            // bias: key kb+4s+r is window col wx0+4s+r -> bq[7-(4s+r)]
            const float* bq = bptr[j] - m * 42;
            float pr0[4], pr1[4];
#pragma unroll
            for (int r = 0; r < 4; ++r)
                pr0[r] = EXP2(fmaf(sf0[r], 0.36067376f, bq[7 - r]));
#pragma unroll
            for (int r = 0; r < 4; ++r)
                pr1[r] = EXP2(fmaf(sf1[r], 0.36067376f, bq[3 - r]));

            const u32x4 pk = (u32x4){ cvtpk(pr0[0], pr0[1]), cvtpk(pr0[2], pr0[3]),
                                      cvtpk(pr1[0], pr1[1]), cvtpk(pr1[2], pr1[3]) };
            const s16x8 pb = *(const s16x8*)&pk;       // PV B-frag: keys kb..kb+7
            accv[j] = __builtin_amdgcn_mfma_f32_16x16x32_bf16(vt,  pb, accv[j], 0, 0, 0);
            accs[j] = __builtin_amdgcn_mfma_f32_16x16x32_bf16(vld, pb, accs[j], 0, 0, 0);
        }
        ak0 = nk0;
        ak1 = nk1;
    }

    // ---- normalize: every accs reg = full masked sum
#pragma unroll
    for (int j = 0; j < 2; ++j) {
        const float inv = 1.0f / accs[j][0];
        *(f32x4*)optr[j] = accv[j] * inv;
    }
}

// ---------------------------------------------------------------------------
extern "C" void kernel_launch(void* const* d_in, const int* in_sizes, int n_in,
                              void* d_out, int out_size, void* d_ws, size_t ws_size,
                              hipStream_t stream) {
    const float* x      = (const float*)d_in[0];
    const float* q_w    = (const float*)d_in[1];
    const float* kv_w   = (const float*)d_in[2];
    const float* pt     = (const float*)d_in[3];
    const float* proj_w = (const float*)d_in[4];
    const float* proj_b = (const float*)d_in[5];
    float* out = (float*)d_out;

    ushort* ykvb = (ushort*)d_ws;                                   // 32 MB head-major
    ushort* qb   = (ushort*)((char*)d_ws + 33554432);               // 16 MB head-major
    ushort* whi  = (ushort*)((char*)d_ws + 33554432 + 16777216);    // 128 KB frag-major
    ushort* wlo  = whi + 65536;                                     // 128 KB
    float*  bias_g = (float*)(wlo + 65536);                         // 14 KB

    conv_w<<<dim3(270), dim3(256), 0, stream>>>(q_w, kv_w, proj_w, pt,
                                                whi, wlo, bias_g);
    gemm_split<<<dim3(512), dim3(256), 0, stream>>>(x, whi, wlo, 0, 3, 1,
                                                    qb, ykvb, nullptr, nullptr);
    halo_attn<<<dim3(256, 8), dim3(512), 0, stream>>>(out, qb, ykvb, bias_g);
    gemm_split<<<dim3(512), dim3(256), 0, stream>>>(out, whi, wlo, 384, 1, 0,
                                                    nullptr, nullptr, out, proj_b);
}

// Round 24
// 87.549 us; speedup vs baseline: 1.3435x; 1.0070x over previous
//
#include <hip/hip_runtime.h>
#include <float.h>

// HaloAttn: x(4,128,128,128) f32 -> out(4,128,128,128) f32
// BS=8, HS=3, WIN=14, NH=8, DQK=DV=16, SCALE=0.25
//
// R24 = R21 exact revert (stride-24 vectorized-bias experiment of R22/R23
// empirically convicted twice; reverted per pre-commitment).
//
// k0: conv_w      weights -> hi/lo bf16 frag-major + PRECOMPUTED bias_g[8][448]
// k1: gemm_split  q=x@q_w^T, kv=x@kv_w^T -> ws bf16 head-major (split MFMA)
// k2: halo_attn   512-thr blocks (4 batches x 2 q-halves), LUT/bias amortized
// k3: gemm_split  d_out = d_out @ proj_w^T + proj_b (in place)
//
// Key space: g = wy*16+wx (wy<14, wx<16; wx>=14 or out-of-image = invalid).
// Permutation (pair m, sub-tile s, A-row i): key = 32m + (i>>2)*8 + 4s + (i&3).
// QK C-frag: lane(lr,cA) reg r holds S for key kb+4s+r, kb=32m+cA*8; those
// keys share window row wy=2m+(cA>>1), wx=(cA&1)*8+(4s+r) -> bias indices
// consecutive descending: bq[7-(4s+r)], bq walks -42/m (pointer-walk).
// Denominator: accs = mfma(valid8, pb, accs) -> every reg = masked sum.
// Invalid keys: bounded-garbage p (K<-pixel 0, guarded bias idx), zeroed
// exactly by vbf (sum) and zeroed V^T rows (PV).
//
// ws: kv[8][65536][32] u16 @0 (32MB) | q[8][65536][16] @32M (16MB)
//   | whi' @48M (128KB) | wlo' (128KB) | bias_g[8][448] f32 (14KB).

typedef float f32x4 __attribute__((ext_vector_type(4)));
typedef short s16x4 __attribute__((ext_vector_type(4)));
typedef short s16x8 __attribute__((ext_vector_type(8)));
typedef unsigned int u32x2 __attribute__((ext_vector_type(2)));
typedef unsigned int u32x4 __attribute__((ext_vector_type(4)));

__device__ inline ushort f2bf(float f) {   // RNE float->bf16 (cold paths)
    unsigned u = __float_as_uint(f);
    return (ushort)((u + 0x7FFF + ((u >> 16) & 1)) >> 16);
}
__device__ inline float bf2f(ushort h) { return __uint_as_float((unsigned)h << 16); }
__device__ inline unsigned cvtpk(float a, float b) {   // D[15:0]=bf16(a), D[31:16]=bf16(b)
    unsigned r;
    asm("v_cvt_pk_bf16_f32 %0, %1, %2" : "=v"(r) : "v"(a), "v"(b));
    return r;
}
#if __has_builtin(__builtin_amdgcn_exp2f)
#define EXP2(x) __builtin_amdgcn_exp2f(x)
#else
#define EXP2(x) exp2f(x)
#endif

// ---------------------------------------------------------------------------
// Weight split (frag-major) + bias table precompute.
__global__ __launch_bounds__(256) void conv_w(
    const float* __restrict__ q_w, const float* __restrict__ kv_w,
    const float* __restrict__ proj_w, const float* __restrict__ pos_table,
    ushort* whi, ushort* wlo, float* bias_g)
{
    if (blockIdx.x < 256) {
        const int g = blockIdx.x * 256 + threadIdx.x;      // 0..65535
        const int row = g >> 7, col = g & 127;
        const float v = (row < 128) ? q_w[row * 128 + col]
                      : (row < 384) ? kv_w[(row - 128) * 128 + col]
                                    : proj_w[(row - 384) * 128 + col];
        const ushort h = f2bf(v);
        const int off = ((row >> 4) * 2048) + ((col >> 3) * 128)
                      + ((row & 15) * 8) + (col & 7);
        whi[off] = h;
        wlo[off] = f2bf(v - bf2f(h));
    } else {
        const int i = (blockIdx.x - 256) * 256 + threadIdx.x;  // 0..3583
        if (i < 8 * 448) {
            const int h = i / 448, e = i - h * 448;
            float v = 0.f;
            if (e >= 2) {                  // logical rel-idx r = e-2 (bounded pad)
                const int r = e - 2, ry = r / 21, rx = r - ry * 21;
                v = pos_table[((ry + 3) * 27 + rx + 3) * 8 + h] * 1.44269504f;
            }
            bias_g[h * 448 + e] = v;
        }
    }
}

// ---------------------------------------------------------------------------
// Split-bf16 MFMA GEMM (R13-proven).
__global__ __launch_bounds__(256) void gemm_split(
    const float* A,                                   // [M][128] fp32
    const ushort* __restrict__ Whi, const ushort* __restrict__ Wlo,
    int wbase, int ntc, int tok1,
    ushort* qb, ushort* kvb, float* outf, const float* __restrict__ bias)
{
    __shared__ ushort Ah[128 * 128];   // [row][k] swizzled 16B chunks, 32KB
    __shared__ ushort Al[128 * 128];

    const int t = threadIdx.x;
    const int row0 = blockIdx.x * 128;
    const int w = t >> 6, l = t & 63;
    const int wm = w >> 1, wn = w & 1;
    const int lr = l & 15, cA = l >> 4;

#pragma unroll
    for (int i = 0; i < 16; ++i) {
        const int idx = t + i * 256;
        const int p = idx >> 5, fc = idx & 31;         // row, float4-col
        const float4 v = *(const float4*)(A + (size_t)(row0 + p) * 128 + fc * 4);
        const int base = p * 128 + (((fc >> 1) ^ (p & 7)) << 3) + (fc & 1) * 4;
        const unsigned h01 = cvtpk(v.x, v.y), h23 = cvtpk(v.z, v.w);
        *(u32x2*)&Ah[base] = (u32x2){h01, h23};
        const float hx = __uint_as_float(h01 << 16);
        const float hy = __uint_as_float(h01 & 0xFFFF0000u);
        const float hz = __uint_as_float(h23 << 16);
        const float hw = __uint_as_float(h23 & 0xFFFF0000u);
        *(u32x2*)&Al[base] = (u32x2){ cvtpk(v.x - hx, v.y - hy),
                                      cvtpk(v.z - hz, v.w - hw) };
    }
    __syncthreads();

#pragma unroll 1
    for (int nt = 0; nt < ntc; ++nt) {
        f32x4 acc[4][4];
#pragma unroll
        for (int mf = 0; mf < 4; ++mf)
#pragma unroll
            for (int nf = 0; nf < 4; ++nf) acc[mf][nf] = (f32x4){0.f,0.f,0.f,0.f};

#pragma unroll 1
        for (int kk = 0; kk < 4; ++kk) {
            s16x8 wh[4], wl[4];
#pragma unroll
            for (int nf = 0; nf < 4; ++nf) {
                const int rb = (wbase >> 4) + nt * 8 + wn * 4 + nf;
                const size_t off = (size_t)rb * 2048 + (kk * 4 + cA) * 128 + lr * 8;
                wh[nf] = *(const s16x8*)&Whi[off];
                wl[nf] = *(const s16x8*)&Wlo[off];
            }
#pragma unroll
            for (int mf = 0; mf < 4; ++mf) {
                const int p = wm * 64 + mf * 16 + lr;
                const int off = p * 128 + ((((kk << 2) + cA) ^ (p & 7)) << 3);
                const s16x8 xh = *(const s16x8*)&Ah[off];
                const s16x8 xl = *(const s16x8*)&Al[off];
#pragma unroll
                for (int nf = 0; nf < 4; ++nf) {
                    acc[mf][nf] = __builtin_amdgcn_mfma_f32_16x16x32_bf16(
                                      wh[nf], xh, acc[mf][nf], 0, 0, 0);
                    acc[mf][nf] = __builtin_amdgcn_mfma_f32_16x16x32_bf16(
                                      wh[nf], xl, acc[mf][nf], 0, 0, 0);
                    acc[mf][nf] = __builtin_amdgcn_mfma_f32_16x16x32_bf16(
                                      wl[nf], xh, acc[mf][nf], 0, 0, 0);
                }
            }
        }

#pragma unroll
        for (int mf = 0; mf < 4; ++mf) {
            const size_t pix = row0 + wm * 64 + mf * 16 + lr;
#pragma unroll
            for (int nf = 0; nf < 4; ++nf) {
                const int chan = wn * 64 + nf * 16 + cA * 4;
                const f32x4 o = acc[mf][nf];
                if (tok1) {
                    const u32x2 pk = (u32x2){ cvtpk(o[0], o[1]), cvtpk(o[2], o[3]) };
                    if (nt == 0) {
                        const int head = wn * 4 + nf;
                        *(u32x2*)(qb + ((size_t)head << 20) + pix * 16 + (chan & 15)) = pk;
                    } else {
                        const int gchan = (nt - 1) * 128 + chan;
                        const int head = gchan >> 5;
                        *(u32x2*)(kvb + ((size_t)head << 21) + pix * 32 + (gchan & 31)) = pk;
                    }
                } else {
                    const float4 bv = *(const float4*)(bias + chan);
                    f32x4 r = o;
                    r[0] += bv.x; r[1] += bv.y; r[2] += bv.z; r[3] += bv.w;
                    *(f32x4*)(outf + pix * 128 + chan) = r;
                }
            }
        }
    }
}

// ---------------------------------------------------------------------------
// MFMA halo attention (R21-proven). grid(256 spatial, 8 head), 512 thr =
// 8 waves = 4 batches x 2 q-halves.
__global__ __launch_bounds__(512) void halo_attn(
    float* out,                           // d_out fp32 (65536 x 128)
    const ushort* __restrict__ qg,        // ws q bf16 [8][65536][16] head-major
    const ushort* __restrict__ kvg,       // ws kv bf16 [8][65536][32] head-major
    const float* __restrict__ bias_g)     // ws bias [8][448] (pre-scaled log2e)
{
    __shared__ ushort VT[4][16][232];     // [batch][dim][key]        29696 B
    __shared__ float  bias_l[448];        // idx -2..445 (2-entry guard)
    __shared__ int    keyoff[256];        // byte offset into kv slice (pad -> 0)
    __shared__ ushort vbf[232];           // valid ? bf16(1.0) : 0

    const int t  = threadIdx.x;
    const int bi = blockIdx.x, head = blockIdx.y;
    const int by = bi >> 4, bx = bi & 15;
    const int w  = t >> 6;
    const int lb = w >> 1;                 // batch 0..3
    const int qh = w & 1;                  // q-half
    const int l  = t & 63;
    const int lr = l & 15;
    const int cA = l >> 4;

    const char* kvh = (const char*)(kvg + ((size_t)head << 21) + ((size_t)lb << 19));

    // ---- per-block LUTs: key g = wy*16+wx (wy = g>>4, wx = g&15)
    if (t < 224) {
        const int wy = t >> 4, wx = t & 15;
        const int py = by * 8 + wy - 3, px = bx * 8 + wx - 3;
        const bool valid = (wx < 14) && ((unsigned)py < 128u) && ((unsigned)px < 128u);
        keyoff[t] = valid ? ((py * 128 + px) * 64) : 0;
        vbf[t]    = valid ? (ushort)0x3F80 : (ushort)0;
    } else if (t < 256) {
        keyoff[t] = 0;                     // prefetch pad
        if (t < 232) vbf[t] = 0;
    }
    for (int i = t; i < 448; i += 512)     // full-coverage bias copy
        bias_l[i] = bias_g[head * 448 + i];
    __syncthreads();

    // ---- stage V^T for all 4 batches: 2 rounds, slb = t>>7, key = (t&127)+128*rd
#pragma unroll
    for (int rd = 0; rd < 2; ++rd) {
        const int key = (t & 127) + rd * 128;
        const int slb = t >> 7;            // 0..3
        if (key < 224) {
            const char* sb = (const char*)(kvg + ((size_t)head << 21)
                             + ((size_t)slb << 19));
            const char* src = sb + keyoff[key] + 32;   // v = d16..31 of record
            const bool valid = vbf[key] != 0;
            const s16x8 z = (s16x8){0,0,0,0,0,0,0,0};
            const s16x8 v0 = valid ? *(const s16x8*)src : z;
            const s16x8 v1 = valid ? *(const s16x8*)(src + 16) : z;
#pragma unroll
            for (int j = 0; j < 8; ++j) {
                VT[slb][j][key]     = (ushort)v0[j];
                VT[slb][j + 8][key] = (ushort)v1[j];
            }
        }
    }
    __syncthreads();

    // ---- per-wave setup: 2 q-tiles (qt = qh*2 + j), batch = lb
    const int gbase = ((lr >> 2) << 3) + (lr & 3);   // key-permutation base
    const int wy0 = cA >> 1, wx0 = (cA & 1) * 8;     // lane's m=0 window row/col
    const ushort* qhp = qg + ((size_t)head << 20);
    s16x8 qf[2];
    float* optr[2];
    const float* bptr[2];
#pragma unroll
    for (int j = 0; j < 2; ++j) {
        const int q = (qh * 2 + j) * 16 + lr;
        const int qy = q >> 3, qx = q & 7;
        const size_t pix = ((size_t)(lb * 128 + by * 8 + qy)) * 128 + bx * 8 + qx;
        optr[j] = out + pix * 128 + head * 16 + cA * 4;
        // idx_min(m=0) = (qy+13-wy0)*21 + (qx+6-wx0); +2 guard offset
        bptr[j] = bias_l + 2 + (qy + 13 - wy0) * 21 + (qx + 6 - wx0);
#pragma unroll
        for (int k = 0; k < 8; ++k) qf[j][k] = 0;
        if (cA < 2)
            qf[j] = *(const s16x8*)(qhp + pix * 16 + cA * 8);
    }

    f32x4 accv[2], accs[2];
#pragma unroll
    for (int j = 0; j < 2; ++j) {
        accv[j] = (f32x4){0.f, 0.f, 0.f, 0.f};
        accs[j] = (f32x4){0.f, 0.f, 0.f, 0.f};
    }

    // prefetch pair 0 (invalid keys read pixel 0 -> bounded garbage, zeroed later)
    s16x8 ak0 = *(const s16x8*)(kvh + keyoff[gbase]     + cA * 16);
    s16x8 ak1 = *(const s16x8*)(kvh + keyoff[gbase + 4] + cA * 16);

#pragma unroll 1
    for (int m = 0; m < 7; ++m) {
        const int nx = 32 * (m + 1) + gbase;           // keyoff padded -> in-bounds
        const s16x8 nk0 = *(const s16x8*)(kvh + keyoff[nx]     + cA * 16);
        const s16x8 nk1 = *(const s16x8*)(kvh + keyoff[nx + 4] + cA * 16);

        const int kb = 32 * m + cA * 8;                 // this lane's 8 keys
        const s16x8 vt  = *(const s16x8*)&VT[lb][lr][kb];  // PV A-frag (dim=lr)
        const s16x8 vld = *(const s16x8*)&vbf[kb];         // sum A-frag

#pragma unroll
        for (int j = 0; j < 2; ++j) {
            const f32x4 sf0 = __builtin_amdgcn_mfma_f32_16x16x32_bf16(
                                  ak0, qf[j], (f32x4){0.f, 0.f, 0.f, 0.f}, 0, 0, 0);
            const f32x4 sf1 = __builtin_amdgcn_mfma_f32_16x16x32_bf16(
                                  ak1, qf[j], (f32x4){0.f, 0.f, 0.f, 0.f}, 0, 0, 0);
            // bias: key kb+4s+r is window col wx0+4s+r -> bq[7-(4s+r)]
            const float* bq = bptr[j] - m * 42;
            float pr0[4], pr1[4];
#pragma unroll
            for (int r = 0; r < 4; ++r)
                pr0[r] = EXP2(fmaf(sf0[r], 0.36067376f, bq[7 - r]));
#pragma unroll
            for (int r = 0; r < 4; ++r)
                pr1[r] = EXP2(fmaf(sf1[r], 0.36067376f, bq[3 - r]));

            const u32x4 pk = (u32x4){ cvtpk(pr0[0], pr0[1]), cvtpk(pr0[2], pr0[3]),
                                      cvtpk(pr1[0], pr1[1]), cvtpk(pr1[2], pr1[3]) };
            const s16x8 pb = *(const s16x8*)&pk;       // PV B-frag: keys kb..kb+7
            accv[j] = __builtin_amdgcn_mfma_f32_16x16x32_bf16(vt,  pb, accv[j], 0, 0, 0);
            accs[j] = __builtin_amdgcn_mfma_f32_16x16x32_bf16(vld, pb, accs[j], 0, 0, 0);
        }
        ak0 = nk0;
        ak1 = nk1;
    }

    // ---- normalize: every accs reg = full masked sum
#pragma unroll
    for (int j = 0; j < 2; ++j) {
        const float inv = 1.0f / accs[j][0];
        *(f32x4*)optr[j] = accv[j] * inv;
    }
}

// ---------------------------------------------------------------------------
extern "C" void kernel_launch(void* const* d_in, const int* in_sizes, int n_in,
                              void* d_out, int out_size, void* d_ws, size_t ws_size,
                              hipStream_t stream) {
    const float* x      = (const float*)d_in[0];
    const float* q_w    = (const float*)d_in[1];
    const float* kv_w   = (const float*)d_in[2];
    const float* pt     = (const float*)d_in[3];
    const float* proj_w = (const float*)d_in[4];
    const float* proj_b = (const float*)d_in[5];
    float* out = (float*)d_out;

    ushort* ykvb = (ushort*)d_ws;                                   // 32 MB head-major
    ushort* qb   = (ushort*)((char*)d_ws + 33554432);               // 16 MB head-major
    ushort* whi  = (ushort*)((char*)d_ws + 33554432 + 16777216);    // 128 KB frag-major
    ushort* wlo  = whi + 65536;                                     // 128 KB
    float*  bias_g = (float*)(wlo + 65536);                         // 14 KB

    conv_w<<<dim3(270), dim3(256), 0, stream>>>(q_w, kv_w, proj_w, pt,
                                                whi, wlo, bias_g);
    gemm_split<<<dim3(512), dim3(256), 0, stream>>>(x, whi, wlo, 0, 3, 1,
                                                    qb, ykvb, nullptr, nullptr);
    halo_attn<<<dim3(256, 8), dim3(512), 0, stream>>>(out, qb, ykvb, bias_g);
    gemm_split<<<dim3(512), dim3(256), 0, stream>>>(out, whi, wlo, 384, 1, 0,
                                                    nullptr, nullptr, out, proj_b);
}